// Round 9
// baseline (5010.694 us; speedup 1.0000x reference)
//
#include <hip/hip_runtime.h>
#include <stdint.h>

typedef __attribute__((ext_vector_type(8))) short s16x8;
typedef __attribute__((ext_vector_type(4))) float f32x4;
typedef __attribute__((ext_vector_type(16))) int i32x16;
typedef uint32_t u32;

#define DEV static __device__ __forceinline__

constexpr int T_ = 1024;

DEV u32 bf16rne(float x){
  u32 u = __float_as_uint(x);
  u = (u + 0x7FFFu + ((u >> 16) & 1u)) >> 16;
  return u;
}
DEV float sigm_(float x){ return 1.f / (1.f + __expf(-x)); }
DEV float tanh_(float x){
  float ax = fabsf(x);
  float e = __expf(-2.f * ax);
  float r = (1.f - e) / (1.f + e);
  return x < 0.f ? -r : r;
}
DEV f32x4 mfma_(s16x8 a, s16x8 b, f32x4 c){
  return __builtin_amdgcn_mfma_f32_16x16x32_bf16(a, b, c, 0, 0, 0);
}

// --- system-coherent (LLC-level) access helpers: bypass L1+L2, NO fences ---
DEV s16x8 ldg_cc16(const short* p){
  s16x8 v;
  asm volatile("global_load_dwordx4 %0, %1, off sc0 sc1"
               : "=v"(v) : "v"(p) : "memory");
  return v;
}
DEV void stg_cc4(short* p, u32 v){
  asm volatile("global_store_dword %0, %1, off sc0 sc1"
               : : "v"(p), "v"(v) : "memory");
}
DEV void stg_cc2(short* p, u32 v){
  asm volatile("global_store_short %0, %1, off sc0 sc1"
               : : "v"(p), "v"(v) : "memory");
}
DEV void stflag_llc(u32* p, u32 v){
  asm volatile("global_store_dword %0, %1, off sc0 sc1" :: "v"(p), "v"(v) : "memory");
}
DEV u32 ldflag_wait_llc(const u32* p){
  u32 v; asm volatile("global_load_dword %0, %1, off sc0 sc1\ns_waitcnt vmcnt(0)" : "=v"(v) : "v"(p) : "memory");
  return v;
}
DEV void wait_vm0(){ asm volatile("s_waitcnt vmcnt(0)" ::: "memory"); }
DEV void pin_v(s16x8 &x){ asm volatile("" : "+v"(x)); }

// ---- explicit-AGPR weight residency (r6, proven) ---------------------------
#define LDW(R, ADDR) asm volatile("global_load_dwordx4 " R ", %0, off" :: "v"(ADDR))
#define MFMA_A(ACC, AF, R) \
  asm volatile("v_mfma_f32_16x16x32_bf16 %0, %1, " R ", %0" : "+v"(ACC) : "v"(AF))
#define MFMA_V(ACC, AF, BV) \
  asm volatile("v_mfma_f32_16x16x32_bf16 %0, %1, %2, %0" : "+v"(ACC) : "v"(AF), "v"(BV))
#define MFMA_AZ(D, AF, R, Z) \
  asm volatile("v_mfma_f32_16x16x32_bf16 %0, %1, " R ", %2" : "=&v"(D) : "v"(AF), "v"(Z))
#define C1S(X, Y, AP, R0, R1) { s16x8 af_ = *(const s16x8*)((AP) + lane*8); \
  MFMA_A(X, af_, R0); MFMA_A(Y, af_, R1); }
#define C1SZ(X, Y, AP, R0, R1, Z) { s16x8 af_ = *(const s16x8*)((AP) + lane*8); \
  MFMA_AZ(X, af_, R0, Z); MFMA_AZ(Y, af_, R1, Z); }
#define C2S(X, AP, R) { s16x8 af_ = *(const s16x8*)((AP) + lane*8); MFMA_A(X, af_, R); }
#define C2SZ(X, AP, R, Z) { s16x8 af_ = *(const s16x8*)((AP) + lane*8); MFMA_AZ(X, af_, R, Z); }
#define POST_NOPS() asm volatile("s_nop 7\ns_nop 7\ns_nop 1") // MFMA D -> VALU read

// flag-line group barrier: parallel arrival stores + 64-lane parallel poll.
// NOUT = this wave's outstanding prefetch LOADS allowed to remain in flight
// (all older stores drained by vmcnt(NOUT) since loads are the newest ops).
template<int NOUT>
DEV void groupbar(u32* flags, int w, u32 target, int tid){
  if constexpr (NOUT == 0)      asm volatile("s_waitcnt vmcnt(0)" ::: "memory");
  else if constexpr (NOUT == 1) asm volatile("s_waitcnt vmcnt(1)" ::: "memory");
  else                          asm volatile("s_waitcnt vmcnt(2)" ::: "memory");
  __syncthreads();
  if (tid == 0) stflag_llc(flags + w, target);
  if (tid < 64){
    const u32* p = flags + (tid & 15);
    while (true){
      u32 v = ldflag_wait_llc(p);
      if (__all((int)(v >= target))) break;
      __builtin_amdgcn_s_sleep(1);
    }
  }
  __syncthreads();
}

// decoder waits for encoder progress: all 16 enc flags >= target
DEV void wait_enc(const u32* flags, u32 target, int tid){
  if (tid < 64){
    const u32* p = flags + (tid & 15);
    while (true){
      u32 v = ldflag_wait_llc(p);
      if (__all((int)(v >= target))) break;
      __builtin_amdgcn_s_sleep(1);
    }
  }
  __syncthreads();
}

// ---------------------------------------------------------------------------
// Fused 2-cell LSTM scan, one batch-group (16 rows) per 16 WGs. (r6 dataflow)
// Weights live in AGPRs: enc W1->a[0:159] W2->a[160:255];
//                        dec W1->a[0:191] W2[0:15]->a[192:255], W2[16:23]->VGPR
// ---------------------------------------------------------------------------
template<int KXB, bool DEC>
DEV void run_scan(const short* __restrict__ xsrc,  // [T][4][KXB][512]
                  short* __restrict__ seq,         // [T+1][4][8][512]
                  short* __restrict__ h1f,         // [2][4][16][512]
                  const short* __restrict__ w1p,
                  const short* __restrict__ w2p,
                  const float* __restrict__ bc1,
                  const float* __restrict__ bc2,
                  u32* mybar, const u32* encbar,
                  int bg, int w,
                  short* lx, short* lh1, short* lh2,
                  float* g1, float* g2, float* c1s, float* c2s,
                  float* b1s, float* b2s)
{
  constexpr int KS1 = KXB + 16;
  constexpr int XB  = KXB/4;
  const int tid  = threadIdx.x;
  const int wv   = tid >> 6;
  const int lane = tid & 63;

  // ---- reserve the ENTIRE AGPR file (forces .agpr_count=256) ----
  i32x16 ag0,ag1,ag2,ag3,ag4,ag5,ag6,ag7,ag8,ag9,ag10,ag11,ag12,ag13,ag14,ag15;
  asm volatile("" : "=a"(ag0),"=a"(ag1),"=a"(ag2),"=a"(ag3),
                    "=a"(ag4),"=a"(ag5),"=a"(ag6),"=a"(ag7));
  asm volatile("" : "=a"(ag8),"=a"(ag9),"=a"(ag10),"=a"(ag11),
                    "=a"(ag12),"=a"(ag13),"=a"(ag14),"=a"(ag15));

  for (int i = tid; i < 16*32; i += 256) c1s[i] = 0.f;
  for (int i = tid; i < 16*16; i += 256) c2s[i] = 0.f;
  if (tid < 128) b1s[tid] = bc1[(tid>>5)*512 + w*32 + (tid&31)];
  if (tid < 64)  b2s[tid] = bc2[(tid>>4)*256 + w*16 + (tid&15)];

  // ---- weights -> architectural AGPRs (one-time) ----
  const int nt0 = wv*32 + w*2;
  const int nt2 = wv*16 + w;
  s16x8 W2v[8];                 // dec-only tail (32 VGPRs)
  {
    const short* b0 = w1p + (size_t)(nt0  )*KS1*512 + lane*8;
    const short* b1 = w1p + (size_t)(nt0+1)*KS1*512 + lane*8;
    const short* b2 = w2p + (size_t)nt2*24*512 + lane*8;
    if constexpr (!DEC){
      LDW("a[0:3]",   b0+0*512);  LDW("a[4:7]",   b0+1*512);  LDW("a[8:11]",  b0+2*512);  LDW("a[12:15]", b0+3*512);
      LDW("a[16:19]", b0+4*512);  LDW("a[20:23]", b0+5*512);  LDW("a[24:27]", b0+6*512);  LDW("a[28:31]", b0+7*512);
      LDW("a[32:35]", b0+8*512);  LDW("a[36:39]", b0+9*512);  LDW("a[40:43]", b0+10*512); LDW("a[44:47]", b0+11*512);
      LDW("a[48:51]", b0+12*512); LDW("a[52:55]", b0+13*512); LDW("a[56:59]", b0+14*512); LDW("a[60:63]", b0+15*512);
      LDW("a[64:67]", b0+16*512); LDW("a[68:71]", b0+17*512); LDW("a[72:75]", b0+18*512); LDW("a[76:79]", b0+19*512);
      LDW("a[80:83]",  b1+0*512);  LDW("a[84:87]",  b1+1*512);  LDW("a[88:91]",  b1+2*512);  LDW("a[92:95]",  b1+3*512);
      LDW("a[96:99]",  b1+4*512);  LDW("a[100:103]",b1+5*512);  LDW("a[104:107]",b1+6*512);  LDW("a[108:111]",b1+7*512);
      LDW("a[112:115]",b1+8*512);  LDW("a[116:119]",b1+9*512);  LDW("a[120:123]",b1+10*512); LDW("a[124:127]",b1+11*512);
      LDW("a[128:131]",b1+12*512); LDW("a[132:135]",b1+13*512); LDW("a[136:139]",b1+14*512); LDW("a[140:143]",b1+15*512);
      LDW("a[144:147]",b1+16*512); LDW("a[148:151]",b1+17*512); LDW("a[152:155]",b1+18*512); LDW("a[156:159]",b1+19*512);
      LDW("a[160:163]",b2+0*512);  LDW("a[164:167]",b2+1*512);  LDW("a[168:171]",b2+2*512);  LDW("a[172:175]",b2+3*512);
      LDW("a[176:179]",b2+4*512);  LDW("a[180:183]",b2+5*512);  LDW("a[184:187]",b2+6*512);  LDW("a[188:191]",b2+7*512);
      LDW("a[192:195]",b2+8*512);  LDW("a[196:199]",b2+9*512);  LDW("a[200:203]",b2+10*512); LDW("a[204:207]",b2+11*512);
      LDW("a[208:211]",b2+12*512); LDW("a[212:215]",b2+13*512); LDW("a[216:219]",b2+14*512); LDW("a[220:223]",b2+15*512);
      LDW("a[224:227]",b2+16*512); LDW("a[228:231]",b2+17*512); LDW("a[232:235]",b2+18*512); LDW("a[236:239]",b2+19*512);
      LDW("a[240:243]",b2+20*512); LDW("a[244:247]",b2+21*512); LDW("a[248:251]",b2+22*512); LDW("a[252:255]",b2+23*512);
    } else {
      LDW("a[0:3]",   b0+0*512);  LDW("a[4:7]",   b0+1*512);  LDW("a[8:11]",  b0+2*512);  LDW("a[12:15]", b0+3*512);
      LDW("a[16:19]", b0+4*512);  LDW("a[20:23]", b0+5*512);  LDW("a[24:27]", b0+6*512);  LDW("a[28:31]", b0+7*512);
      LDW("a[32:35]", b0+8*512);  LDW("a[36:39]", b0+9*512);  LDW("a[40:43]", b0+10*512); LDW("a[44:47]", b0+11*512);
      LDW("a[48:51]", b0+12*512); LDW("a[52:55]", b0+13*512); LDW("a[56:59]", b0+14*512); LDW("a[60:63]", b0+15*512);
      LDW("a[64:67]", b0+16*512); LDW("a[68:71]", b0+17*512); LDW("a[72:75]", b0+18*512); LDW("a[76:79]", b0+19*512);
      LDW("a[80:83]", b0+20*512); LDW("a[84:87]", b0+21*512); LDW("a[88:91]", b0+22*512); LDW("a[92:95]", b0+23*512);
      LDW("a[96:99]",  b1+0*512);  LDW("a[100:103]",b1+1*512);  LDW("a[104:107]",b1+2*512);  LDW("a[108:111]",b1+3*512);
      LDW("a[112:115]",b1+4*512);  LDW("a[116:119]",b1+5*512);  LDW("a[120:123]",b1+6*512);  LDW("a[124:127]",b1+7*512);
      LDW("a[128:131]",b1+8*512);  LDW("a[132:135]",b1+9*512);  LDW("a[136:139]",b1+10*512); LDW("a[140:143]",b1+11*512);
      LDW("a[144:147]",b1+12*512); LDW("a[148:151]",b1+13*512); LDW("a[152:155]",b1+14*512); LDW("a[156:159]",b1+15*512);
      LDW("a[160:163]",b1+16*512); LDW("a[164:167]",b1+17*512); LDW("a[168:171]",b1+18*512); LDW("a[172:175]",b1+19*512);
      LDW("a[176:179]",b1+20*512); LDW("a[180:183]",b1+21*512); LDW("a[184:187]",b1+22*512); LDW("a[188:191]",b1+23*512);
      LDW("a[192:195]",b2+0*512);  LDW("a[196:199]",b2+1*512);  LDW("a[200:203]",b2+2*512);  LDW("a[204:207]",b2+3*512);
      LDW("a[208:211]",b2+4*512);  LDW("a[212:215]",b2+5*512);  LDW("a[216:219]",b2+6*512);  LDW("a[220:223]",b2+7*512);
      LDW("a[224:227]",b2+8*512);  LDW("a[228:231]",b2+9*512);  LDW("a[232:235]",b2+10*512); LDW("a[236:239]",b2+11*512);
      LDW("a[240:243]",b2+12*512); LDW("a[244:247]",b2+13*512); LDW("a[248:251]",b2+14*512); LDW("a[252:255]",b2+15*512);
      #pragma unroll
      for (int i = 0; i < 8; ++i){
        W2v[i] = *(const s16x8*)(b2 + (16+i)*512);
        pin_v(W2v[i]);
      }
    }
    asm volatile("s_waitcnt vmcnt(0)" ::: "memory");
  }

  // persistent zero C-operand (opaque: not rematerializable near MFMAs)
  f32x4 zz = {0.f,0.f,0.f,0.f};
  asm volatile("" : "+v"(zz));

  // ---- prologue: stage h1_{-1} (zeros, parity 1) and x_0 ----
  {
    const short* h1src = h1f + (1*4 + bg)*16*512 + lane*8;
    s16x8 bh1[4];
    #pragma unroll
    for (int c = 0; c < 4; ++c) bh1[c] = ldg_cc16(h1src + (c*4+wv)*512);
    if constexpr (DEC) wait_enc(encbar, 2u, tid);      // z_0 drained
    const short* xs = xsrc + (0*4 + bg)*KXB*512 + lane*8;
    s16x8 bx[XB];
    #pragma unroll
    for (int c = 0; c < XB; ++c)
      bx[c] = DEC ? ldg_cc16(xs + (c*4+wv)*512)
                  : *(const s16x8*)(xs + (c*4+wv)*512);
    wait_vm0();
    #pragma unroll
    for (int c = 0; c < 4; ++c) *(s16x8*)(lh1 + (c*4+wv)*512 + lane*8) = bh1[c];
    #pragma unroll
    for (int c = 0; c < XB; ++c) *(s16x8*)(lx + (c*4+wv)*512 + lane*8) = bx[c];
  }
  __syncthreads();

  for (int t = 0; t < T_; ++t){
    // ---- cell1: wave wv = gate wv, cols w*32..+32, 4 partial accs ----
    f32x4 a0a = {0,0,0,0}, a0b = {0,0,0,0}, a1a = {0,0,0,0}, a1b = {0,0,0,0};
    if constexpr (!DEC){
      C1SZ(a0a,a1a, lx +0*512, "a[0:3]",  "a[80:83]", zz);
      C1SZ(a0b,a1b, lx +1*512, "a[4:7]",  "a[84:87]", zz);
      C1S(a0a,a1a, lx +2*512, "a[8:11]", "a[88:91]");
      C1S(a0b,a1b, lx +3*512, "a[12:15]","a[92:95]");
      C1S(a0a,a1a, lh1+0*512, "a[16:19]","a[96:99]");
      C1S(a0b,a1b, lh1+1*512, "a[20:23]","a[100:103]");
      C1S(a0a,a1a, lh1+2*512, "a[24:27]","a[104:107]");
      C1S(a0b,a1b, lh1+3*512, "a[28:31]","a[108:111]");
      C1S(a0a,a1a, lh1+4*512, "a[32:35]","a[112:115]");
      C1S(a0b,a1b, lh1+5*512, "a[36:39]","a[116:119]");
      C1S(a0a,a1a, lh1+6*512, "a[40:43]","a[120:123]");
      C1S(a0b,a1b, lh1+7*512, "a[44:47]","a[124:127]");
      C1S(a0a,a1a, lh1+8*512, "a[48:51]","a[128:131]");
      C1S(a0b,a1b, lh1+9*512, "a[52:55]","a[132:135]");
      C1S(a0a,a1a, lh1+10*512,"a[56:59]","a[136:139]");
      C1S(a0b,a1b, lh1+11*512,"a[60:63]","a[140:143]");
      C1S(a0a,a1a, lh1+12*512,"a[64:67]","a[144:147]");
      C1S(a0b,a1b, lh1+13*512,"a[68:71]","a[148:151]");
      C1S(a0a,a1a, lh1+14*512,"a[72:75]","a[152:155]");
      C1S(a0b,a1b, lh1+15*512,"a[76:79]","a[156:159]");
    } else {
      C1SZ(a0a,a1a, lx +0*512, "a[0:3]",  "a[96:99]", zz);
      C1SZ(a0b,a1b, lx +1*512, "a[4:7]",  "a[100:103]", zz);
      C1S(a0a,a1a, lx +2*512, "a[8:11]", "a[104:107]");
      C1S(a0b,a1b, lx +3*512, "a[12:15]","a[108:111]");
      C1S(a0a,a1a, lx +4*512, "a[16:19]","a[112:115]");
      C1S(a0b,a1b, lx +5*512, "a[20:23]","a[116:119]");
      C1S(a0a,a1a, lx +6*512, "a[24:27]","a[120:123]");
      C1S(a0b,a1b, lx +7*512, "a[28:31]","a[124:127]");
      C1S(a0a,a1a, lh1+0*512, "a[32:35]","a[128:131]");
      C1S(a0b,a1b, lh1+1*512, "a[36:39]","a[132:135]");
      C1S(a0a,a1a, lh1+2*512, "a[40:43]","a[136:139]");
      C1S(a0b,a1b, lh1+3*512, "a[44:47]","a[140:143]");
      C1S(a0a,a1a, lh1+4*512, "a[48:51]","a[144:147]");
      C1S(a0b,a1b, lh1+5*512, "a[52:55]","a[148:151]");
      C1S(a0a,a1a, lh1+6*512, "a[56:59]","a[152:155]");
      C1S(a0b,a1b, lh1+7*512, "a[60:63]","a[156:159]");
      C1S(a0a,a1a, lh1+8*512, "a[64:67]","a[160:163]");
      C1S(a0b,a1b, lh1+9*512, "a[68:71]","a[164:167]");
      C1S(a0a,a1a, lh1+10*512,"a[72:75]","a[168:171]");
      C1S(a0b,a1b, lh1+11*512,"a[76:79]","a[172:175]");
      C1S(a0a,a1a, lh1+12*512,"a[80:83]","a[176:179]");
      C1S(a0b,a1b, lh1+13*512,"a[84:87]","a[180:183]");
      C1S(a0a,a1a, lh1+14*512,"a[88:91]","a[184:187]");
      C1S(a0b,a1b, lh1+15*512,"a[92:95]","a[188:191]");
    }
    POST_NOPS();
    {
      const f32x4 acc0 = a0a + a0b, acc1 = a1a + a1b;
      const int r0 = (lane>>4)*4, cc = lane & 15;
      #pragma unroll
      for (int j = 0; j < 4; ++j){
        g1[wv*528 + (r0+j)*33 + cc]      = acc0[j];
        g1[wv*528 + (r0+j)*33 + 16 + cc] = acc1[j];
      }
    }
    __syncthreads();

    // ---- elementwise: h1 slice [16 x 32], 2 outputs/thread ----
    {
      short* h1dst = h1f + (((t&1)*4 + bg)*16 + w)*512;
      const int idx = tid << 1;
      const int r = idx >> 5;
      const int c = idx & 31;        // even
      float hv0 = 0.f, hv1 = 0.f;
      #pragma unroll
      for (int p = 0; p < 2; ++p){
        const int cp = c + p;
        const float xi = g1[0*528 + r*33+cp] + b1s[0*32+cp];
        const float xf = g1[1*528 + r*33+cp] + b1s[1*32+cp];
        const float xg = g1[2*528 + r*33+cp] + b1s[2*32+cp];
        const float xo = g1[3*528 + r*33+cp] + b1s[3*32+cp];
        const float ii = sigm_(xi), ff = sigm_(xf), oo = sigm_(xo);
        const float gg = tanh_(xg);
        const float cn = ff * c1s[r*32+cp] + ii * gg;
        c1s[r*32+cp] = cn;
        const float hv = oo * tanh_(cn);
        if (p == 0) hv0 = hv; else hv1 = hv;
      }
      const u32 pk = bf16rne(hv0) | (bf16rne(hv1) << 16);
      stg_cc4(h1dst + ((((c>>3)<<4) + r) << 3) + (c & 7), pk);
    }

    // ---- enc-progress poll + next x/z prefetch (overlap h1-store drain) ----
    const int tn = (t+1 < T_) ? (t+1) : (T_-1);
    if constexpr (DEC) wait_enc(encbar, (u32)(tn+2), tid);
    s16x8 bx[XB];
    {
      const short* xs = xsrc + (tn*4 + bg)*KXB*512 + lane*8;
      #pragma unroll
      for (int c = 0; c < XB; ++c)
        bx[c] = DEC ? ldg_cc16(xs + (c*4+wv)*512)
                    : *(const s16x8*)(xs + (c*4+wv)*512);
    }

    // arrival waits only for stores (vmcnt(XB) leaves prefetch loads in flight)
    groupbar<XB>(mybar, w, (u32)(t+1), tid);

    // ---- stage: h1_t (16 blk), h2_{t-1} (8 blk) via LLC; x from prefetch ----
    {
      const short* h1src = h1f + ((t&1)*4 + bg)*16*512 + lane*8;
      const short* h2src = seq + (t*4 + bg)*8*512 + lane*8;
      s16x8 bh1[4], bh2[2];
      #pragma unroll
      for (int c = 0; c < 4; ++c) bh1[c] = ldg_cc16(h1src + (c*4+wv)*512);
      #pragma unroll
      for (int c = 0; c < 2; ++c) bh2[c] = ldg_cc16(h2src + (c*4+wv)*512);
      wait_vm0();
      #pragma unroll
      for (int c = 0; c < 4; ++c) *(s16x8*)(lh1 + (c*4+wv)*512 + lane*8) = bh1[c];
      #pragma unroll
      for (int c = 0; c < 2; ++c) *(s16x8*)(lh2 + (c*4+wv)*512 + lane*8) = bh2[c];
      #pragma unroll
      for (int c = 0; c < XB; ++c) *(s16x8*)(lx + (c*4+wv)*512 + lane*8) = bx[c];
    }
    __syncthreads();

    // ---- cell2: A = [h1_t | h2_{t-1}], 2 partial accs ----
    f32x4 aca = {0,0,0,0}, acb = {0,0,0,0};
    if constexpr (!DEC){
      C2SZ(aca, lh1+0*512, "a[160:163]", zz); C2SZ(acb, lh1+1*512, "a[164:167]", zz);
      C2S(aca, lh1+2*512, "a[168:171]"); C2S(acb, lh1+3*512, "a[172:175]");
      C2S(aca, lh1+4*512, "a[176:179]"); C2S(acb, lh1+5*512, "a[180:183]");
      C2S(aca, lh1+6*512, "a[184:187]"); C2S(acb, lh1+7*512, "a[188:191]");
      C2S(aca, lh1+8*512, "a[192:195]"); C2S(acb, lh1+9*512, "a[196:199]");
      C2S(aca, lh1+10*512,"a[200:203]"); C2S(acb, lh1+11*512,"a[204:207]");
      C2S(aca, lh1+12*512,"a[208:211]"); C2S(acb, lh1+13*512,"a[212:215]");
      C2S(aca, lh1+14*512,"a[216:219]"); C2S(acb, lh1+15*512,"a[220:223]");
      C2S(aca, lh2+0*512, "a[224:227]"); C2S(acb, lh2+1*512, "a[228:231]");
      C2S(aca, lh2+2*512, "a[232:235]"); C2S(acb, lh2+3*512, "a[236:239]");
      C2S(aca, lh2+4*512, "a[240:243]"); C2S(acb, lh2+5*512, "a[244:247]");
      C2S(aca, lh2+6*512, "a[248:251]"); C2S(acb, lh2+7*512, "a[252:255]");
    } else {
      C2SZ(aca, lh1+0*512, "a[192:195]", zz); C2SZ(acb, lh1+1*512, "a[196:199]", zz);
      C2S(aca, lh1+2*512, "a[200:203]"); C2S(acb, lh1+3*512, "a[204:207]");
      C2S(aca, lh1+4*512, "a[208:211]"); C2S(acb, lh1+5*512, "a[212:215]");
      C2S(aca, lh1+6*512, "a[216:219]"); C2S(acb, lh1+7*512, "a[220:223]");
      C2S(aca, lh1+8*512, "a[224:227]"); C2S(acb, lh1+9*512, "a[228:231]");
      C2S(aca, lh1+10*512,"a[232:235]"); C2S(acb, lh1+11*512,"a[236:239]");
      C2S(aca, lh1+12*512,"a[240:243]"); C2S(acb, lh1+13*512,"a[244:247]");
      C2S(aca, lh1+14*512,"a[248:251]"); C2S(acb, lh1+15*512,"a[252:255]");
      #pragma unroll
      for (int i = 0; i < 8; ++i){
        s16x8 af_ = *(const s16x8*)(lh2 + i*512 + lane*8);
        if (i & 1) MFMA_V(acb, af_, W2v[i]);
        else       MFMA_V(aca, af_, W2v[i]);
      }
    }
    POST_NOPS();
    {
      const f32x4 acc = aca + acb;
      const int r0 = (lane>>4)*4, cc = lane & 15;
      #pragma unroll
      for (int j = 0; j < 4; ++j) g2[wv*272 + (r0+j)*17 + cc] = acc[j];
    }
    __syncthreads();
    {
      short* odst = seq + ((t+1)*4 + bg)*8*512;
      const int r = tid >> 4, c = tid & 15;
      const float xi = g2[0*272 + r*17+c] + b2s[0*16+c];
      const float xf = g2[1*272 + r*17+c] + b2s[1*16+c];
      const float xg = g2[2*272 + r*17+c] + b2s[2*16+c];
      const float xo = g2[3*272 + r*17+c] + b2s[3*16+c];
      const float ii = sigm_(xi), ff = sigm_(xf), oo = sigm_(xo);
      const float gg = tanh_(xg);
      const float cn = ff * c2s[r*16+c] + ii * gg;
      c2s[r*16+c] = cn;
      const float hv = oo * tanh_(cn);
      const int jj = ((w & 1) << 4) + c;
      stg_cc2(odst + (((w>>1)*64 + ((jj>>3)<<4) + r) << 3) + (jj & 7), bf16rne(hv));
    }
  }

  if constexpr (!DEC){
    // signal final cell2 (z_1023) stores drained: flag = T_+1
    wait_vm0();
    __syncthreads();
    if (tid == 0) stflag_llc(mybar + w, (u32)(T_+1));
  }

  // keep the AGPR reservation live through the whole kernel
  asm volatile("" :: "a"(ag0),"a"(ag1),"a"(ag2),"a"(ag3),
                     "a"(ag4),"a"(ag5),"a"(ag6),"a"(ag7));
  asm volatile("" :: "a"(ag8),"a"(ag9),"a"(ag10),"a"(ag11),
                     "a"(ag12),"a"(ag13),"a"(ag14),"a"(ag15));
}

__launch_bounds__(256, 1)
__global__ void scan2(const short* __restrict__ xp,
                      short* __restrict__ zfrag, short* __restrict__ dfrag,
                      short* __restrict__ h1e, short* __restrict__ h1d,
                      const short* __restrict__ enc1p, const short* __restrict__ enc2p,
                      const short* __restrict__ dec1p, const short* __restrict__ dec2p,
                      const float* __restrict__ bc1e, const float* __restrict__ bc2e,
                      const float* __restrict__ bc1d, const float* __restrict__ bc2d,
                      u32* __restrict__ bar)
{
  __shared__ short lx[8*512];
  __shared__ short lh1[16*512];
  __shared__ short lh2[8*512];
  __shared__ float g1[4*528];
  __shared__ float g2[4*272];
  __shared__ float c1s[16*32];
  __shared__ float c2s[16*16];
  __shared__ float b1s[128];
  __shared__ float b2s[64];

  const int b = blockIdx.x;
  if (b < 64){
    const int bg = b >> 4, w = b & 15;
    run_scan<4, false>(xp, zfrag, h1e, enc1p, enc2p, bc1e, bc2e,
                       bar + bg*32, nullptr, bg, w,
                       lx, lh1, lh2, g1, g2, c1s, c2s, b1s, b2s);
  } else {
    const int bb = b - 64, bg = bb >> 4, w = bb & 15;
    run_scan<8, true>(zfrag + 4*8*512, dfrag, h1d, dec1p, dec2p, bc1d, bc2d,
                      bar + (4 + bg)*32, bar + bg*32, bg, w,
                      lx, lh1, lh2, g1, g2, c1s, c2s, b1s, b2s);
  }
}

// ---------------------------------------------------------------------------
// fused fc1(relu)+fc2 over one t-slice (64 rows) per block
// ---------------------------------------------------------------------------
__launch_bounds__(256, 1)
__global__ void fc_kernel(const short* __restrict__ dfrag, // [T+1][4][8][512]
                          const short* __restrict__ fc1p,  // [32][8][512]
                          const short* __restrict__ fc2p,  // [8][16][512]
                          const float* __restrict__ fc1b,  // [512]
                          float* __restrict__ out)         // [64][1024][128]
{
  const int t = blockIdx.x;
  const int tid = threadIdx.x, wv = tid >> 6, lane = tid & 63;
  __shared__ short hl[4*16*512];
  const short* A = dfrag + (size_t)(t+1)*4*8*512;

  f32x4 acc[4][8];
  #pragma unroll
  for (int mt = 0; mt < 4; ++mt)
    #pragma unroll
    for (int nt = 0; nt < 8; ++nt) acc[mt][nt] = (f32x4){0.f,0.f,0.f,0.f};

  #pragma unroll
  for (int ks = 0; ks < 8; ++ks){
    s16x8 a[4];
    #pragma unroll
    for (int mt = 0; mt < 4; ++mt) a[mt] = *(const s16x8*)(A + (mt*8+ks)*512 + lane*8);
    #pragma unroll
    for (int nt = 0; nt < 8; ++nt){
      s16x8 bq = *(const s16x8*)(fc1p + (((wv*8+nt)*8 + ks)*64 + lane)*8);
      #pragma unroll
      for (int mt = 0; mt < 4; ++mt) acc[mt][nt] = mfma_(a[mt], bq, acc[mt][nt]);
    }
  }
  const int r0 = (lane>>4)*4, c15 = lane & 15;
  #pragma unroll
  for (int nt = 0; nt < 8; ++nt){
    const int col = wv*128 + nt*16 + c15;
    const float bia = fc1b[col];
    const int ks2 = col >> 5, lp = (((col & 31) >> 3) << 4), e = col & 7;
    #pragma unroll
    for (int mt = 0; mt < 4; ++mt)
      #pragma unroll
      for (int j = 0; j < 4; ++j){
        float v = acc[mt][nt][j] + bia;
        v = v > 0.f ? v : 0.f;
        hl[(mt*16 + ks2)*512 + (lp + r0 + j)*8 + e] = (short)bf16rne(v);
      }
  }
  __syncthreads();

  f32x4 a2[4][2];
  #pragma unroll
  for (int mt = 0; mt < 4; ++mt)
    #pragma unroll
    for (int nt = 0; nt < 2; ++nt) a2[mt][nt] = (f32x4){0.f,0.f,0.f,0.f};
  #pragma unroll
  for (int ks = 0; ks < 16; ++ks){
    s16x8 a[4];
    #pragma unroll
    for (int mt = 0; mt < 4; ++mt) a[mt] = *(const s16x8*)(hl + (mt*16+ks)*512 + lane*8);
    #pragma unroll
    for (int nt = 0; nt < 2; ++nt){
      s16x8 bq = *(const s16x8*)(fc2p + (((wv*2+nt)*16 + ks)*64 + lane)*8);
      #pragma unroll
      for (int mt = 0; mt < 4; ++mt) a2[mt][nt] = mfma_(a[mt], bq, a2[mt][nt]);
    }
  }
  #pragma unroll
  for (int mt = 0; mt < 4; ++mt)
    #pragma unroll
    for (int nt = 0; nt < 2; ++nt)
      #pragma unroll
      for (int j = 0; j < 4; ++j){
        const int b_  = mt*16 + r0 + j;
        const int col = wv*32 + nt*16 + c15;
        out[((size_t)b_*1024 + t)*128 + col] = a2[mt][nt][j];
      }
}

// ---------------------------------------------------------------------------
// packing kernels
// ---------------------------------------------------------------------------
__global__ void pack_w(const float* __restrict__ src1, int K1,
                       const float* __restrict__ src2, int K2,
                       int N, short* __restrict__ dst)
{
  const int KS = (K1 + K2) >> 5;
  const int total = (N >> 4) * KS * 64;
  const int tid = blockIdx.x*256 + threadIdx.x;
  if (tid >= total) return;
  const int lane = tid & 63;
  const int rest = tid >> 6;
  const int ks = rest % KS;
  const int ntile = rest / KS;
  const int n = ntile*16 + (lane & 15);
  const int k = ks*32 + ((lane >> 4) << 3);
  const float* s; int kk, stride;
  if (k < K1){ s = src1; kk = k;      stride = K1; }
  else       { s = src2; kk = k - K1; stride = K2; }
  const float4 f0 = *(const float4*)(s + n*stride + kk);
  const float4 f1 = *(const float4*)(s + n*stride + kk + 4);
  s16x8 r;
  r[0] = (short)bf16rne(f0.x); r[1] = (short)bf16rne(f0.y);
  r[2] = (short)bf16rne(f0.z); r[3] = (short)bf16rne(f0.w);
  r[4] = (short)bf16rne(f1.x); r[5] = (short)bf16rne(f1.y);
  r[6] = (short)bf16rne(f1.z); r[7] = (short)bf16rne(f1.w);
  *(s16x8*)(dst + tid*8) = r;
}

__global__ void pack_x_k(const float* __restrict__ x, short* __restrict__ xp){
  const int tid = blockIdx.x*256 + threadIdx.x;
  const int lane = tid & 63;
  const int ks = (tid >> 6) & 3;
  const int bg = (tid >> 8) & 3;
  const int t  = tid >> 10;
  const int b  = bg*16 + (lane & 15);
  const int k  = ks*32 + ((lane >> 4) << 3);
  const float* s = x + (b*1024 + t)*128 + k;
  const float4 f0 = *(const float4*)s;
  const float4 f1 = *(const float4*)(s + 4);
  s16x8 r;
  r[0] = (short)bf16rne(f0.x); r[1] = (short)bf16rne(f0.y);
  r[2] = (short)bf16rne(f0.z); r[3] = (short)bf16rne(f0.w);
  r[4] = (short)bf16rne(f1.x); r[5] = (short)bf16rne(f1.y);
  r[6] = (short)bf16rne(f1.z); r[7] = (short)bf16rne(f1.w);
  *(s16x8*)(xp + (size_t)tid*8) = r;
}

__global__ void addv(const float* __restrict__ a, const float* __restrict__ b,
                     float* __restrict__ o, int n){
  const int i = blockIdx.x*256 + threadIdx.x;
  if (i < n) o[i] = a[i] + b[i];
}

// ---------------------------------------------------------------------------
extern "C" void kernel_launch(void* const* d_in, const int* in_sizes, int n_in,
                              void* d_out, int out_size, void* d_ws, size_t ws_size,
                              hipStream_t stream)
{
  (void)in_sizes; (void)n_in; (void)out_size; (void)ws_size;
  const float* x     = (const float*)d_in[0];
  const float* eWih1 = (const float*)d_in[1];
  const float* eWhh1 = (const float*)d_in[2];
  const float* ebih1 = (const float*)d_in[3];
  const float* ebhh1 = (const float*)d_in[4];
  const float* eWih2 = (const float*)d_in[5];
  const float* eWhh2 = (const float*)d_in[6];
  const float* ebih2 = (const float*)d_in[7];
  const float* ebhh2 = (const float*)d_in[8];
  const float* dWih1 = (const float*)d_in[9];
  const float* dWhh1 = (const float*)d_in[10];
  const float* dbih1 = (const float*)d_in[11];
  const float* dbhh1 = (const float*)d_in[12];
  const float* dWih2 = (const float*)d_in[13];
  const float* dWhh2 = (const float*)d_in[14];
  const float* dbih2 = (const float*)d_in[15];
  const float* dbhh2 = (const float*)d_in[16];
  const float* fc1w  = (const float*)d_in[17];
  const float* fc1b  = (const float*)d_in[18];
  const float* fc2w  = (const float*)d_in[19];
  float* out = (float*)d_out;
  char* ws = (char*)d_ws;

  size_t off = 0;
  auto alloc = [&](size_t bytes){ size_t o = off; off += (bytes + 255) & ~(size_t)255; return o; };
  const size_t ENC1P = alloc(128*20*512*2);
  const size_t ENC2P = alloc(64*24*512*2);
  const size_t DEC1P = alloc(128*24*512*2);
  const size_t DEC2P = alloc(64*24*512*2);
  const size_t FC1P  = alloc(32*8*512*2);
  const size_t FC2P  = alloc(8*16*512*2);
  const size_t BC1E  = alloc(2048*4);
  const size_t BC2E  = alloc(1024*4);
  const size_t BC1D  = alloc(2048*4);
  const size_t BC2D  = alloc(1024*4);
  const size_t XP    = alloc((size_t)1024*4*4*512*2);
  const size_t ZFRAG = alloc((size_t)1025*4*8*512*2);
  const size_t DFRAG = alloc((size_t)1025*4*8*512*2);
  const size_t H1E   = alloc(2*4*16*512*2);
  const size_t H1D   = alloc(2*4*16*512*2);
  const size_t BAR   = alloc(8192);

  short* enc1p = (short*)(ws + ENC1P);
  short* enc2p = (short*)(ws + ENC2P);
  short* dec1p = (short*)(ws + DEC1P);
  short* dec2p = (short*)(ws + DEC2P);
  short* fc1p  = (short*)(ws + FC1P);
  short* fc2p  = (short*)(ws + FC2P);
  float* bc1e  = (float*)(ws + BC1E);
  float* bc2e  = (float*)(ws + BC2E);
  float* bc1d  = (float*)(ws + BC1D);
  float* bc2d  = (float*)(ws + BC2D);
  short* xp    = (short*)(ws + XP);
  short* zfrag = (short*)(ws + ZFRAG);
  short* dfrag = (short*)(ws + DFRAG);
  short* h1e   = (short*)(ws + H1E);
  short* h1d   = (short*)(ws + H1D);
  u32*   bar   = (u32*)(ws + BAR);

  hipMemsetAsync(zfrag, 0, 4*8*512*2, stream);          // z slot 0 (h2 state t=0)
  hipMemsetAsync(dfrag, 0, 4*8*512*2, stream);
  hipMemsetAsync(h1e, 0, 2*4*16*512*2, stream);
  hipMemsetAsync(h1d, 0, 2*4*16*512*2, stream);
  hipMemsetAsync(bar, 0, 8192, stream);                 // flag lines

  pack_w<<<640, 256, 0, stream>>>(eWih1, 128, eWhh1, 512, 2048, enc1p);
  pack_w<<<384, 256, 0, stream>>>(eWih2, 512, eWhh2, 256, 1024, enc2p);
  pack_w<<<768, 256, 0, stream>>>(dWih1, 256, dWhh1, 512, 2048, dec1p);
  pack_w<<<384, 256, 0, stream>>>(dWih2, 512, dWhh2, 256, 1024, dec2p);
  pack_w<<<64,  256, 0, stream>>>(fc1w,  256, fc1w,  0,   512,  fc1p);
  pack_w<<<32,  256, 0, stream>>>(fc2w,  512, fc2w,  0,   128,  fc2p);
  addv<<<8, 256, 0, stream>>>(ebih1, ebhh1, bc1e, 2048);
  addv<<<4, 256, 0, stream>>>(ebih2, ebhh2, bc2e, 1024);
  addv<<<8, 256, 0, stream>>>(dbih1, dbhh1, bc1d, 2048);
  addv<<<4, 256, 0, stream>>>(dbih2, dbhh2, bc2d, 1024);
  pack_x_k<<<4096, 256, 0, stream>>>(x, xp);

  scan2<<<128, 256, 0, stream>>>(xp, zfrag, dfrag, h1e, h1d,
                                 enc1p, enc2p, dec1p, dec2p,
                                 bc1e, bc2e, bc1d, bc2d, bar);
  fc_kernel<<<1024, 256, 0, stream>>>(dfrag, fc1p, fc2p, fc1b, out);
}

// Round 10
// 4361.872 us; speedup vs baseline: 1.1487x; 1.1487x over previous
//
#include <hip/hip_runtime.h>
#include <stdint.h>

typedef __attribute__((ext_vector_type(8))) short s16x8;
typedef __attribute__((ext_vector_type(4))) float f32x4;
typedef __attribute__((ext_vector_type(16))) int i32x16;
typedef uint32_t u32;

#define DEV static __device__ __forceinline__

constexpr int T_ = 1024;

DEV u32 bf16rne(float x){
  u32 u = __float_as_uint(x);
  u = (u + 0x7FFFu + ((u >> 16) & 1u)) >> 16;
  return u;
}
DEV float sigm_(float x){ return 1.f / (1.f + __expf(-x)); }
DEV float tanh_(float x){
  float ax = fabsf(x);
  float e = __expf(-2.f * ax);
  float r = (1.f - e) / (1.f + e);
  return x < 0.f ? -r : r;
}
DEV f32x4 mfma_(s16x8 a, s16x8 b, f32x4 c){
  return __builtin_amdgcn_mfma_f32_16x16x32_bf16(a, b, c, 0, 0, 0);
}
DEV void wait_vm0(){ asm volatile("s_waitcnt vmcnt(0)" ::: "memory"); }
DEV void pin_v(s16x8 &x){ asm volatile("" : "+v"(x)); }

// ---- LLC-coherent primitives (sc0 sc1 — proven r2-r9) ----------------------
DEV s16x8 ldg_cc16(const short* p){
  s16x8 v; asm volatile("global_load_dwordx4 %0, %1, off sc0 sc1" : "=v"(v) : "v"(p) : "memory"); return v;
}
DEV void stg_cc2(short* p, u32 v){
  asm volatile("global_store_short %0, %1, off sc0 sc1" :: "v"(p), "v"(v) : "memory");
}
DEV void stflag_llc(u32* p, u32 v){
  asm volatile("global_store_dword %0, %1, off sc0 sc1" :: "v"(p), "v"(v) : "memory");
}
DEV u32 ldflag_wait_llc(const u32* p){
  u32 v; asm volatile("global_load_dword %0, %1, off sc0 sc1\ns_waitcnt vmcnt(0)" : "=v"(v) : "v"(p) : "memory");
  return v;
}
// ---- XCD-local (sc0-only) primitives — used ONLY after probe validation ----
DEV s16x8 ld16_x(const short* p){
  s16x8 v; asm volatile("global_load_dwordx4 %0, %1, off sc0" : "=v"(v) : "v"(p) : "memory"); return v;
}
DEV void st4_x(short* p, u32 v){
  asm volatile("global_store_dword %0, %1, off sc0" :: "v"(p), "v"(v) : "memory");
}
DEV void st2_x(short* p, u32 v){
  asm volatile("global_store_short %0, %1, off sc0" :: "v"(p), "v"(v) : "memory");
}
DEV void stflag_x(u32* p, u32 v){
  asm volatile("global_store_dword %0, %1, off sc0" :: "v"(p), "v"(v) : "memory");
}
DEV u32 ldflag_wait_x(const u32* p){
  u32 v; asm volatile("global_load_dword %0, %1, off sc0\ns_waitcnt vmcnt(0)" : "=v"(v) : "v"(p) : "memory");
  return v;
}
DEV void stprobe(u32* p, u32 v){
  asm volatile("global_store_dword %0, %1, off sc0" :: "v"(p), "v"(v) : "memory");
}
DEV u32 ldprobe(const u32* p){
  u32 v; asm volatile("global_load_dword %0, %1, off sc0\ns_waitcnt vmcnt(0)" : "=v"(v) : "v"(p) : "memory");
  return v;
}
// dual-path data helpers (fast is wave-uniform)
DEV s16x8 ld16f(bool fast, const short* p){ return fast ? ld16_x(p) : ldg_cc16(p); }
DEV void st4f(bool fast, short* p, u32 v){
  if (fast) st4_x(p, v);
  else asm volatile("global_store_dword %0, %1, off sc0 sc1" :: "v"(p), "v"(v) : "memory");
}
DEV void st2f(bool fast, short* p, u32 v){ if (fast) st2_x(p, v); else stg_cc2(p, v); }

// ---- explicit-AGPR weight residency (r6, proven) ---------------------------
#define LDW(R, ADDR) asm volatile("global_load_dwordx4 " R ", %0, off" :: "v"(ADDR))
#define MFMA_A(ACC, AF, R) \
  asm volatile("v_mfma_f32_16x16x32_bf16 %0, %1, " R ", %0" : "+v"(ACC) : "v"(AF))
#define MFMA_V(ACC, AF, BV) \
  asm volatile("v_mfma_f32_16x16x32_bf16 %0, %1, %2, %0" : "+v"(ACC) : "v"(AF), "v"(BV))
#define MFMA_AZ(D, AF, R, Z) \
  asm volatile("v_mfma_f32_16x16x32_bf16 %0, %1, " R ", %2" : "=&v"(D) : "v"(AF), "v"(Z))
#define C1S(X, Y, AP, R0, R1) { s16x8 af_ = *(const s16x8*)((AP) + lane*8); \
  MFMA_A(X, af_, R0); MFMA_A(Y, af_, R1); }
#define C1SZ(X, Y, AP, R0, R1, Z) { s16x8 af_ = *(const s16x8*)((AP) + lane*8); \
  MFMA_AZ(X, af_, R0, Z); MFMA_AZ(Y, af_, R1, Z); }
#define C2S(X, AP, R) { s16x8 af_ = *(const s16x8*)((AP) + lane*8); MFMA_A(X, af_, R); }
#define C2SZ(X, AP, R, Z) { s16x8 af_ = *(const s16x8*)((AP) + lane*8); MFMA_AZ(X, af_, R, Z); }
#define POST_NOPS() asm volatile("s_nop 7\ns_nop 7\ns_nop 1") // MFMA D -> VALU read

// LLC flag-line barrier (r9, proven). flags: [0..15]
template<int NOUT>
DEV void groupbar_llc(u32* flags, int w, u32 target, int tid){
  if constexpr (NOUT == 0)      asm volatile("s_waitcnt vmcnt(0)" ::: "memory");
  else if constexpr (NOUT == 1) asm volatile("s_waitcnt vmcnt(1)" ::: "memory");
  else                          asm volatile("s_waitcnt vmcnt(2)" ::: "memory");
  __syncthreads();
  if (tid == 0) stflag_llc(flags + w, target);
  if (tid < 64){
    const u32* p = flags + (tid & 15);
    while (true){
      u32 v = ldflag_wait_llc(p);
      if (__all((int)(v >= target))) break;
      __builtin_amdgcn_s_sleep(1);
    }
  }
  __syncthreads();
}

// dual-mode barrier. flags layout: [0..15] primary, [16..31] LLC twin.
// FAST: sc0 flags + hard spin, LLC-twin timeout check (hang-proof).
// encf != nullptr (enc only): also publish progress to the LLC line for dec.
template<int NOUT>
DEV void groupbar2(bool fast, u32* flags, u32* encf, int w, u32 target, int tid){
  if constexpr (NOUT == 0)      asm volatile("s_waitcnt vmcnt(0)" ::: "memory");
  else if constexpr (NOUT == 1) asm volatile("s_waitcnt vmcnt(1)" ::: "memory");
  else                          asm volatile("s_waitcnt vmcnt(2)" ::: "memory");
  __syncthreads();
  if (tid == 0){
    if (encf) stflag_llc(encf + w, target);
    if (fast){ stflag_x(flags + w, target); stflag_llc(flags + 16 + w, target); }
    else stflag_llc(flags + w, target);
  }
  if (tid < 64){
    if (fast){
      const u32* p  = flags + (tid & 15);
      const u32* p2 = flags + 16 + (tid & 15);
      u32 it = 0;
      while (true){
        u32 v = ldflag_wait_x(p);
        if (__all((int)(v >= target))) break;
        if (((++it) & 511u) == 0u){
          u32 v2 = ldflag_wait_llc(p2);
          if (__all((int)(v2 >= target))) break;
        }
      }
    } else {
      const u32* p = flags + (tid & 15);
      while (true){
        u32 v = ldflag_wait_llc(p);
        if (__all((int)(v >= target))) break;
        __builtin_amdgcn_s_sleep(1);
      }
    }
  }
  __syncthreads();
}

// decoder waits for encoder progress (LLC line, always)
DEV void wait_enc(const u32* flags, u32 target, int tid){
  if (tid < 64){
    const u32* p = flags + (tid & 15);
    while (true){
      u32 v = ldflag_wait_llc(p);
      if (__all((int)(v >= target))) break;
      __builtin_amdgcn_s_sleep(1);
    }
  }
  __syncthreads();
}

// ---------------------------------------------------------------------------
// XCD-coherence probe: 2 rounds of {sc0 write pattern -> LLC barrier ->
// sc0 read-verify all 16 slices -> LLC barrier}. Round 2 re-reads the SAME
// addresses with a different pattern -> detects stale-cache behavior.
// ---------------------------------------------------------------------------
DEV bool probe_xcd(u32* prb, u32* pbf, u32* okf, int w, int tid, int* sscr){
  bool ok = true;
  #pragma unroll 1
  for (int round = 0; round < 2; ++round){
    const u32 salt = round ? 0xA5A5A5A5u : 0x5A5A5A5Au;
    u32 val = salt ^ ((u32)w << 20) ^ ((u32)tid * 2654435761u);
    stprobe(prb + w*256 + tid, val);
    groupbar_llc<0>(pbf, w, (u32)(round*2 + 1), tid);
    #pragma unroll 1
    for (int s = 0; s < 16; ++s){
      u32 exp = salt ^ ((u32)s << 20) ^ ((u32)tid * 2654435761u);
      u32 got = ldprobe(prb + s*256 + tid);
      ok &= (got == exp);
    }
    groupbar_llc<0>(pbf, w, (u32)(round*2 + 2), tid);
  }
  unsigned long long b = __ballot(ok);
  if ((tid & 63) == 0) sscr[tid >> 6] = (b == ~0ull) ? 1 : 0;
  __syncthreads();
  const int wgok = sscr[0] & sscr[1] & sscr[2] & sscr[3];
  __syncthreads();
  if (tid == 0) stflag_llc(okf + w, (u32)(1 + wgok));
  int fastv = 0;
  if (tid < 64){
    const u32* p = okf + (tid & 15);
    u32 v = 0;
    while (true){
      v = ldflag_wait_llc(p);
      if (__all((int)(v >= 1u))) break;
      __builtin_amdgcn_s_sleep(1);
    }
    fastv = __all((int)(v == 2u)) ? 1 : 0;
  }
  __syncthreads();
  if (tid == 0) sscr[4] = fastv;
  __syncthreads();
  return sscr[4] != 0;
}

// ---------------------------------------------------------------------------
// Fused 2-cell LSTM scan, one batch-group (16 rows) per 16 WGs. (r9 dataflow)
// fast: intra-group h1/h2 exchange + flags via XCD-local L2 (probe-verified).
// enc z export + enc progress flags: always LLC (cross-group/XCD).
// ---------------------------------------------------------------------------
template<int KXB, bool DEC>
DEV void run_scan(const short* __restrict__ xsrc,  // [T][4][KXB][512]
                  short* __restrict__ seq,         // [T+1][4][8][512]
                  short* __restrict__ h1f,         // [2][4][16][512]
                  const short* __restrict__ w1p,
                  const short* __restrict__ w2p,
                  const float* __restrict__ bc1,
                  const float* __restrict__ bc2,
                  u32* mybar, u32* encf, bool fast,
                  int bg, int w,
                  short* lx, short* lh1, short* lh2,
                  float* g1, float* g2, float* c1s, float* c2s,
                  float* b1s, float* b2s)
{
  constexpr int KS1 = KXB + 16;
  constexpr int XB  = KXB/4;
  const int tid  = threadIdx.x;
  const int wv   = tid >> 6;
  const int lane = tid & 63;

  // ---- reserve the ENTIRE AGPR file (forces .agpr_count=256) ----
  i32x16 ag0,ag1,ag2,ag3,ag4,ag5,ag6,ag7,ag8,ag9,ag10,ag11,ag12,ag13,ag14,ag15;
  asm volatile("" : "=a"(ag0),"=a"(ag1),"=a"(ag2),"=a"(ag3),
                    "=a"(ag4),"=a"(ag5),"=a"(ag6),"=a"(ag7));
  asm volatile("" : "=a"(ag8),"=a"(ag9),"=a"(ag10),"=a"(ag11),
                    "=a"(ag12),"=a"(ag13),"=a"(ag14),"=a"(ag15));

  for (int i = tid; i < 16*32; i += 256) c1s[i] = 0.f;
  for (int i = tid; i < 16*16; i += 256) c2s[i] = 0.f;
  if (tid < 128) b1s[tid] = bc1[(tid>>5)*512 + w*32 + (tid&31)];
  if (tid < 64)  b2s[tid] = bc2[(tid>>4)*256 + w*16 + (tid&15)];

  // ---- weights -> architectural AGPRs (one-time) ----
  const int nt0 = wv*32 + w*2;
  const int nt2 = wv*16 + w;
  s16x8 W2v[8];                 // dec-only tail (32 VGPRs)
  {
    const short* b0 = w1p + (size_t)(nt0  )*KS1*512 + lane*8;
    const short* b1 = w1p + (size_t)(nt0+1)*KS1*512 + lane*8;
    const short* b2 = w2p + (size_t)nt2*24*512 + lane*8;
    if constexpr (!DEC){
      LDW("a[0:3]",   b0+0*512);  LDW("a[4:7]",   b0+1*512);  LDW("a[8:11]",  b0+2*512);  LDW("a[12:15]", b0+3*512);
      LDW("a[16:19]", b0+4*512);  LDW("a[20:23]", b0+5*512);  LDW("a[24:27]", b0+6*512);  LDW("a[28:31]", b0+7*512);
      LDW("a[32:35]", b0+8*512);  LDW("a[36:39]", b0+9*512);  LDW("a[40:43]", b0+10*512); LDW("a[44:47]", b0+11*512);
      LDW("a[48:51]", b0+12*512); LDW("a[52:55]", b0+13*512); LDW("a[56:59]", b0+14*512); LDW("a[60:63]", b0+15*512);
      LDW("a[64:67]", b0+16*512); LDW("a[68:71]", b0+17*512); LDW("a[72:75]", b0+18*512); LDW("a[76:79]", b0+19*512);
      LDW("a[80:83]",  b1+0*512);  LDW("a[84:87]",  b1+1*512);  LDW("a[88:91]",  b1+2*512);  LDW("a[92:95]",  b1+3*512);
      LDW("a[96:99]",  b1+4*512);  LDW("a[100:103]",b1+5*512);  LDW("a[104:107]",b1+6*512);  LDW("a[108:111]",b1+7*512);
      LDW("a[112:115]",b1+8*512);  LDW("a[116:119]",b1+9*512);  LDW("a[120:123]",b1+10*512); LDW("a[124:127]",b1+11*512);
      LDW("a[128:131]",b1+12*512); LDW("a[132:135]",b1+13*512); LDW("a[136:139]",b1+14*512); LDW("a[140:143]",b1+15*512);
      LDW("a[144:147]",b1+16*512); LDW("a[148:151]",b1+17*512); LDW("a[152:155]",b1+18*512); LDW("a[156:159]",b1+19*512);
      LDW("a[160:163]",b2+0*512);  LDW("a[164:167]",b2+1*512);  LDW("a[168:171]",b2+2*512);  LDW("a[172:175]",b2+3*512);
      LDW("a[176:179]",b2+4*512);  LDW("a[180:183]",b2+5*512);  LDW("a[184:187]",b2+6*512);  LDW("a[188:191]",b2+7*512);
      LDW("a[192:195]",b2+8*512);  LDW("a[196:199]",b2+9*512);  LDW("a[200:203]",b2+10*512); LDW("a[204:207]",b2+11*512);
      LDW("a[208:211]",b2+12*512); LDW("a[212:215]",b2+13*512); LDW("a[216:219]",b2+14*512); LDW("a[220:223]",b2+15*512);
      LDW("a[224:227]",b2+16*512); LDW("a[228:231]",b2+17*512); LDW("a[232:235]",b2+18*512); LDW("a[236:239]",b2+19*512);
      LDW("a[240:243]",b2+20*512); LDW("a[244:247]",b2+21*512); LDW("a[248:251]",b2+22*512); LDW("a[252:255]",b2+23*512);
    } else {
      LDW("a[0:3]",   b0+0*512);  LDW("a[4:7]",   b0+1*512);  LDW("a[8:11]",  b0+2*512);  LDW("a[12:15]", b0+3*512);
      LDW("a[16:19]", b0+4*512);  LDW("a[20:23]", b0+5*512);  LDW("a[24:27]", b0+6*512);  LDW("a[28:31]", b0+7*512);
      LDW("a[32:35]", b0+8*512);  LDW("a[36:39]", b0+9*512);  LDW("a[40:43]", b0+10*512); LDW("a[44:47]", b0+11*512);
      LDW("a[48:51]", b0+12*512); LDW("a[52:55]", b0+13*512); LDW("a[56:59]", b0+14*512); LDW("a[60:63]", b0+15*512);
      LDW("a[64:67]", b0+16*512); LDW("a[68:71]", b0+17*512); LDW("a[72:75]", b0+18*512); LDW("a[76:79]", b0+19*512);
      LDW("a[80:83]", b0+20*512); LDW("a[84:87]", b0+21*512); LDW("a[88:91]", b0+22*512); LDW("a[92:95]", b0+23*512);
      LDW("a[96:99]",  b1+0*512);  LDW("a[100:103]",b1+1*512);  LDW("a[104:107]",b1+2*512);  LDW("a[108:111]",b1+3*512);
      LDW("a[112:115]",b1+4*512);  LDW("a[116:119]",b1+5*512);  LDW("a[120:123]",b1+6*512);  LDW("a[124:127]",b1+7*512);
      LDW("a[128:131]",b1+8*512);  LDW("a[132:135]",b1+9*512);  LDW("a[136:139]",b1+10*512); LDW("a[140:143]",b1+11*512);
      LDW("a[144:147]",b1+12*512); LDW("a[148:151]",b1+13*512); LDW("a[152:155]",b1+14*512); LDW("a[156:159]",b1+15*512);
      LDW("a[160:163]",b1+16*512); LDW("a[164:167]",b1+17*512); LDW("a[168:171]",b1+18*512); LDW("a[172:175]",b1+19*512);
      LDW("a[176:179]",b1+20*512); LDW("a[180:183]",b1+21*512); LDW("a[184:187]",b1+22*512); LDW("a[188:191]",b1+23*512);
      LDW("a[192:195]",b2+0*512);  LDW("a[196:199]",b2+1*512);  LDW("a[200:203]",b2+2*512);  LDW("a[204:207]",b2+3*512);
      LDW("a[208:211]",b2+4*512);  LDW("a[212:215]",b2+5*512);  LDW("a[216:219]",b2+6*512);  LDW("a[220:223]",b2+7*512);
      LDW("a[224:227]",b2+8*512);  LDW("a[228:231]",b2+9*512);  LDW("a[232:235]",b2+10*512); LDW("a[236:239]",b2+11*512);
      LDW("a[240:243]",b2+12*512); LDW("a[244:247]",b2+13*512); LDW("a[248:251]",b2+14*512); LDW("a[252:255]",b2+15*512);
      #pragma unroll
      for (int i = 0; i < 8; ++i){
        W2v[i] = *(const s16x8*)(b2 + (16+i)*512);
        pin_v(W2v[i]);
      }
    }
    asm volatile("s_waitcnt vmcnt(0)" ::: "memory");
  }

  // persistent zero C-operand
  f32x4 zz = {0.f,0.f,0.f,0.f};
  asm volatile("" : "+v"(zz));

  // ---- prologue: stage h1_{-1} (zeros, parity 1) and x_0 ----
  {
    const short* h1src = h1f + (1*4 + bg)*16*512 + lane*8;
    s16x8 bh1[4];
    #pragma unroll
    for (int c = 0; c < 4; ++c) bh1[c] = ldg_cc16(h1src + (c*4+wv)*512);
    if constexpr (DEC) wait_enc(encf, 2u, tid);        // z_0 drained
    const short* xs = xsrc + (0*4 + bg)*KXB*512 + lane*8;
    s16x8 bx[XB];
    #pragma unroll
    for (int c = 0; c < XB; ++c)
      bx[c] = DEC ? ldg_cc16(xs + (c*4+wv)*512)
                  : *(const s16x8*)(xs + (c*4+wv)*512);
    wait_vm0();
    #pragma unroll
    for (int c = 0; c < 4; ++c) *(s16x8*)(lh1 + (c*4+wv)*512 + lane*8) = bh1[c];
    #pragma unroll
    for (int c = 0; c < XB; ++c) *(s16x8*)(lx + (c*4+wv)*512 + lane*8) = bx[c];
  }
  __syncthreads();

  for (int t = 0; t < T_; ++t){
    // ---- cell1 ----
    f32x4 a0a = {0,0,0,0}, a0b = {0,0,0,0}, a1a = {0,0,0,0}, a1b = {0,0,0,0};
    if constexpr (!DEC){
      C1SZ(a0a,a1a, lx +0*512, "a[0:3]",  "a[80:83]", zz);
      C1SZ(a0b,a1b, lx +1*512, "a[4:7]",  "a[84:87]", zz);
      C1S(a0a,a1a, lx +2*512, "a[8:11]", "a[88:91]");
      C1S(a0b,a1b, lx +3*512, "a[12:15]","a[92:95]");
      C1S(a0a,a1a, lh1+0*512, "a[16:19]","a[96:99]");
      C1S(a0b,a1b, lh1+1*512, "a[20:23]","a[100:103]");
      C1S(a0a,a1a, lh1+2*512, "a[24:27]","a[104:107]");
      C1S(a0b,a1b, lh1+3*512, "a[28:31]","a[108:111]");
      C1S(a0a,a1a, lh1+4*512, "a[32:35]","a[112:115]");
      C1S(a0b,a1b, lh1+5*512, "a[36:39]","a[116:119]");
      C1S(a0a,a1a, lh1+6*512, "a[40:43]","a[120:123]");
      C1S(a0b,a1b, lh1+7*512, "a[44:47]","a[124:127]");
      C1S(a0a,a1a, lh1+8*512, "a[48:51]","a[128:131]");
      C1S(a0b,a1b, lh1+9*512, "a[52:55]","a[132:135]");
      C1S(a0a,a1a, lh1+10*512,"a[56:59]","a[136:139]");
      C1S(a0b,a1b, lh1+11*512,"a[60:63]","a[140:143]");
      C1S(a0a,a1a, lh1+12*512,"a[64:67]","a[144:147]");
      C1S(a0b,a1b, lh1+13*512,"a[68:71]","a[148:151]");
      C1S(a0a,a1a, lh1+14*512,"a[72:75]","a[152:155]");
      C1S(a0b,a1b, lh1+15*512,"a[76:79]","a[156:159]");
    } else {
      C1SZ(a0a,a1a, lx +0*512, "a[0:3]",  "a[96:99]", zz);
      C1SZ(a0b,a1b, lx +1*512, "a[4:7]",  "a[100:103]", zz);
      C1S(a0a,a1a, lx +2*512, "a[8:11]", "a[104:107]");
      C1S(a0b,a1b, lx +3*512, "a[12:15]","a[108:111]");
      C1S(a0a,a1a, lx +4*512, "a[16:19]","a[112:115]");
      C1S(a0b,a1b, lx +5*512, "a[20:23]","a[116:119]");
      C1S(a0a,a1a, lx +6*512, "a[24:27]","a[120:123]");
      C1S(a0b,a1b, lx +7*512, "a[28:31]","a[124:127]");
      C1S(a0a,a1a, lh1+0*512, "a[32:35]","a[128:131]");
      C1S(a0b,a1b, lh1+1*512, "a[36:39]","a[132:135]");
      C1S(a0a,a1a, lh1+2*512, "a[40:43]","a[136:139]");
      C1S(a0b,a1b, lh1+3*512, "a[44:47]","a[140:143]");
      C1S(a0a,a1a, lh1+4*512, "a[48:51]","a[144:147]");
      C1S(a0b,a1b, lh1+5*512, "a[52:55]","a[148:151]");
      C1S(a0a,a1a, lh1+6*512, "a[56:59]","a[152:155]");
      C1S(a0b,a1b, lh1+7*512, "a[60:63]","a[156:159]");
      C1S(a0a,a1a, lh1+8*512, "a[64:67]","a[160:163]");
      C1S(a0b,a1b, lh1+9*512, "a[68:71]","a[164:167]");
      C1S(a0a,a1a, lh1+10*512,"a[72:75]","a[168:171]");
      C1S(a0b,a1b, lh1+11*512,"a[76:79]","a[172:175]");
      C1S(a0a,a1a, lh1+12*512,"a[80:83]","a[176:179]");
      C1S(a0b,a1b, lh1+13*512,"a[84:87]","a[180:183]");
      C1S(a0a,a1a, lh1+14*512,"a[88:91]","a[184:187]");
      C1S(a0b,a1b, lh1+15*512,"a[92:95]","a[188:191]");
    }
    POST_NOPS();
    {
      const f32x4 acc0 = a0a + a0b, acc1 = a1a + a1b;
      const int r0 = (lane>>4)*4, cc = lane & 15;
      #pragma unroll
      for (int j = 0; j < 4; ++j){
        g1[wv*528 + (r0+j)*33 + cc]      = acc0[j];
        g1[wv*528 + (r0+j)*33 + 16 + cc] = acc1[j];
      }
    }
    __syncthreads();

    // ---- elementwise: h1 slice ----
    {
      short* h1dst = h1f + (((t&1)*4 + bg)*16 + w)*512;
      const int idx = tid << 1;
      const int r = idx >> 5;
      const int c = idx & 31;
      float hv0 = 0.f, hv1 = 0.f;
      #pragma unroll
      for (int p = 0; p < 2; ++p){
        const int cp = c + p;
        const float xi = g1[0*528 + r*33+cp] + b1s[0*32+cp];
        const float xf = g1[1*528 + r*33+cp] + b1s[1*32+cp];
        const float xg = g1[2*528 + r*33+cp] + b1s[2*32+cp];
        const float xo = g1[3*528 + r*33+cp] + b1s[3*32+cp];
        const float ii = sigm_(xi), ff = sigm_(xf), oo = sigm_(xo);
        const float gg = tanh_(xg);
        const float cn = ff * c1s[r*32+cp] + ii * gg;
        c1s[r*32+cp] = cn;
        const float hv = oo * tanh_(cn);
        if (p == 0) hv0 = hv; else hv1 = hv;
      }
      const u32 pk = bf16rne(hv0) | (bf16rne(hv1) << 16);
      st4f(fast, h1dst + ((((c>>3)<<4) + r) << 3) + (c & 7), pk);
    }

    // ---- enc-progress poll + next x/z prefetch (overlaps h1-store drain) ----
    const int tn = (t+1 < T_) ? (t+1) : (T_-1);
    if constexpr (DEC) wait_enc(encf, (u32)(tn+2), tid);
    s16x8 bx[XB];
    {
      const short* xs = xsrc + (tn*4 + bg)*KXB*512 + lane*8;
      #pragma unroll
      for (int c = 0; c < XB; ++c)
        bx[c] = DEC ? ldg_cc16(xs + (c*4+wv)*512)
                    : *(const s16x8*)(xs + (c*4+wv)*512);
    }

    groupbar2<XB>(fast, mybar, DEC ? nullptr : encf, w, (u32)(t+1), tid);

    // ---- stage: h1_t, h2_{t-1}; x from prefetch ----
    {
      const short* h1src = h1f + ((t&1)*4 + bg)*16*512 + lane*8;
      const short* h2src = seq + (t*4 + bg)*8*512 + lane*8;
      s16x8 bh1[4], bh2[2];
      #pragma unroll
      for (int c = 0; c < 4; ++c) bh1[c] = ld16f(fast, h1src + (c*4+wv)*512);
      #pragma unroll
      for (int c = 0; c < 2; ++c)
        bh2[c] = DEC ? ld16f(fast, h2src + (c*4+wv)*512)
                     : ldg_cc16(h2src + (c*4+wv)*512);
      wait_vm0();
      #pragma unroll
      for (int c = 0; c < 4; ++c) *(s16x8*)(lh1 + (c*4+wv)*512 + lane*8) = bh1[c];
      #pragma unroll
      for (int c = 0; c < 2; ++c) *(s16x8*)(lh2 + (c*4+wv)*512 + lane*8) = bh2[c];
      #pragma unroll
      for (int c = 0; c < XB; ++c) *(s16x8*)(lx + (c*4+wv)*512 + lane*8) = bx[c];
    }
    __syncthreads();

    // ---- cell2 ----
    f32x4 aca = {0,0,0,0}, acb = {0,0,0,0};
    if constexpr (!DEC){
      C2SZ(aca, lh1+0*512, "a[160:163]", zz); C2SZ(acb, lh1+1*512, "a[164:167]", zz);
      C2S(aca, lh1+2*512, "a[168:171]"); C2S(acb, lh1+3*512, "a[172:175]");
      C2S(aca, lh1+4*512, "a[176:179]"); C2S(acb, lh1+5*512, "a[180:183]");
      C2S(aca, lh1+6*512, "a[184:187]"); C2S(acb, lh1+7*512, "a[188:191]");
      C2S(aca, lh1+8*512, "a[192:195]"); C2S(acb, lh1+9*512, "a[196:199]");
      C2S(aca, lh1+10*512,"a[200:203]"); C2S(acb, lh1+11*512,"a[204:207]");
      C2S(aca, lh1+12*512,"a[208:211]"); C2S(acb, lh1+13*512,"a[212:215]");
      C2S(aca, lh1+14*512,"a[216:219]"); C2S(acb, lh1+15*512,"a[220:223]");
      C2S(aca, lh2+0*512, "a[224:227]"); C2S(acb, lh2+1*512, "a[228:231]");
      C2S(aca, lh2+2*512, "a[232:235]"); C2S(acb, lh2+3*512, "a[236:239]");
      C2S(aca, lh2+4*512, "a[240:243]"); C2S(acb, lh2+5*512, "a[244:247]");
      C2S(aca, lh2+6*512, "a[248:251]"); C2S(acb, lh2+7*512, "a[252:255]");
    } else {
      C2SZ(aca, lh1+0*512, "a[192:195]", zz); C2SZ(acb, lh1+1*512, "a[196:199]", zz);
      C2S(aca, lh1+2*512, "a[200:203]"); C2S(acb, lh1+3*512, "a[204:207]");
      C2S(aca, lh1+4*512, "a[208:211]"); C2S(acb, lh1+5*512, "a[212:215]");
      C2S(aca, lh1+6*512, "a[216:219]"); C2S(acb, lh1+7*512, "a[220:223]");
      C2S(aca, lh1+8*512, "a[224:227]"); C2S(acb, lh1+9*512, "a[228:231]");
      C2S(aca, lh1+10*512,"a[232:235]"); C2S(acb, lh1+11*512,"a[236:239]");
      C2S(aca, lh1+12*512,"a[240:243]"); C2S(acb, lh1+13*512,"a[244:247]");
      C2S(aca, lh1+14*512,"a[248:251]"); C2S(acb, lh1+15*512,"a[252:255]");
      #pragma unroll
      for (int i = 0; i < 8; ++i){
        s16x8 af_ = *(const s16x8*)(lh2 + i*512 + lane*8);
        if (i & 1) MFMA_V(acb, af_, W2v[i]);
        else       MFMA_V(aca, af_, W2v[i]);
      }
    }
    POST_NOPS();
    {
      const f32x4 acc = aca + acb;
      const int r0 = (lane>>4)*4, cc = lane & 15;
      #pragma unroll
      for (int j = 0; j < 4; ++j) g2[wv*272 + (r0+j)*17 + cc] = acc[j];
    }
    __syncthreads();
    {
      short* odst = seq + ((t+1)*4 + bg)*8*512;
      const int r = tid >> 4, c = tid & 15;
      const float xi = g2[0*272 + r*17+c] + b2s[0*16+c];
      const float xf = g2[1*272 + r*17+c] + b2s[1*16+c];
      const float xg = g2[2*272 + r*17+c] + b2s[2*16+c];
      const float xo = g2[3*272 + r*17+c] + b2s[3*16+c];
      const float ii = sigm_(xi), ff = sigm_(xf), oo = sigm_(xo);
      const float gg = tanh_(xg);
      const float cn = ff * c2s[r*16+c] + ii * gg;
      c2s[r*16+c] = cn;
      const float hv = oo * tanh_(cn);
      const int jj = ((w & 1) << 4) + c;
      const int off = (((w>>1)*64 + ((jj>>3)<<4) + r) << 3) + (jj & 7);
      if constexpr (DEC) st2f(fast, odst + off, bf16rne(hv));
      else stg_cc2(odst + off, bf16rne(hv));   // cross-group: dec reads via LLC
    }
  }

  if constexpr (!DEC){
    wait_vm0();
    __syncthreads();
    if (tid == 0) stflag_llc(encf + w, (u32)(T_+1));
  }

  asm volatile("" :: "a"(ag0),"a"(ag1),"a"(ag2),"a"(ag3),
                     "a"(ag4),"a"(ag5),"a"(ag6),"a"(ag7));
  asm volatile("" :: "a"(ag8),"a"(ag9),"a"(ag10),"a"(ag11),
                     "a"(ag12),"a"(ag13),"a"(ag14),"a"(ag15));
}

// group gg = blockIdx&7 (16 WGs, stride 8 -> one XCD under round-robin
// dispatch; verified by the probe, NOT assumed). gg 0..3 enc, 4..7 dec.
__launch_bounds__(256, 1)
__global__ void scan2(const short* __restrict__ xp,
                      short* __restrict__ zfrag, short* __restrict__ dfrag,
                      short* __restrict__ h1e, short* __restrict__ h1d,
                      const short* __restrict__ enc1p, const short* __restrict__ enc2p,
                      const short* __restrict__ dec1p, const short* __restrict__ dec2p,
                      const float* __restrict__ bc1e, const float* __restrict__ bc2e,
                      const float* __restrict__ bc1d, const float* __restrict__ bc2d,
                      u32* __restrict__ bar, u32* __restrict__ prb)
{
  __shared__ short lx[8*512];
  __shared__ short lh1[16*512];
  __shared__ short lh2[8*512];
  __shared__ float g1[4*528];
  __shared__ float g2[4*272];
  __shared__ float c1s[16*32];
  __shared__ float c2s[16*16];
  __shared__ float b1s[128];
  __shared__ float b2s[64];
  __shared__ int sscr[8];

  const int b  = blockIdx.x;
  const int gg = b & 7;
  const int w  = b >> 3;
  const bool isdec = (gg >= 4);
  const int bg = isdec ? (gg - 4) : gg;

  // one-time XCD-coherence probe for this group (LLC-synced, hang-free)
  const bool fast = probe_xcd(prb + gg*4096, bar + 1024 + gg*16,
                              bar + 1280 + gg*16, w, threadIdx.x, sscr);

  u32* myflags = bar + gg*32;           // [0..15] primary, [16..31] LLC twin
  u32* encf    = bar + 512 + bg*16;     // enc progress (LLC, cross-group)

  if (!isdec){
    run_scan<4, false>(xp, zfrag, h1e, enc1p, enc2p, bc1e, bc2e,
                       myflags, encf, fast, bg, w,
                       lx, lh1, lh2, g1, g2, c1s, c2s, b1s, b2s);
  } else {
    run_scan<8, true>(zfrag + 4*8*512, dfrag, h1d, dec1p, dec2p, bc1d, bc2d,
                      myflags, encf, fast, bg, w,
                      lx, lh1, lh2, g1, g2, c1s, c2s, b1s, b2s);
  }
}

// ---------------------------------------------------------------------------
// fused fc1(relu)+fc2 over one t-slice (64 rows) per block  (unchanged)
// ---------------------------------------------------------------------------
__launch_bounds__(256, 1)
__global__ void fc_kernel(const short* __restrict__ dfrag,
                          const short* __restrict__ fc1p,
                          const short* __restrict__ fc2p,
                          const float* __restrict__ fc1b,
                          float* __restrict__ out)
{
  const int t = blockIdx.x;
  const int tid = threadIdx.x, wv = tid >> 6, lane = tid & 63;
  __shared__ short hl[4*16*512];
  const short* A = dfrag + (size_t)(t+1)*4*8*512;

  f32x4 acc[4][8];
  #pragma unroll
  for (int mt = 0; mt < 4; ++mt)
    #pragma unroll
    for (int nt = 0; nt < 8; ++nt) acc[mt][nt] = (f32x4){0.f,0.f,0.f,0.f};

  #pragma unroll
  for (int ks = 0; ks < 8; ++ks){
    s16x8 a[4];
    #pragma unroll
    for (int mt = 0; mt < 4; ++mt) a[mt] = *(const s16x8*)(A + (mt*8+ks)*512 + lane*8);
    #pragma unroll
    for (int nt = 0; nt < 8; ++nt){
      s16x8 bq = *(const s16x8*)(fc1p + (((wv*8+nt)*8 + ks)*64 + lane)*8);
      #pragma unroll
      for (int mt = 0; mt < 4; ++mt) acc[mt][nt] = mfma_(a[mt], bq, acc[mt][nt]);
    }
  }
  const int r0 = (lane>>4)*4, c15 = lane & 15;
  #pragma unroll
  for (int nt = 0; nt < 8; ++nt){
    const int col = wv*128 + nt*16 + c15;
    const float bia = fc1b[col];
    const int ks2 = col >> 5, lp = (((col & 31) >> 3) << 4), e = col & 7;
    #pragma unroll
    for (int mt = 0; mt < 4; ++mt)
      #pragma unroll
      for (int j = 0; j < 4; ++j){
        float v = acc[mt][nt][j] + bia;
        v = v > 0.f ? v : 0.f;
        hl[(mt*16 + ks2)*512 + (lp + r0 + j)*8 + e] = (short)bf16rne(v);
      }
  }
  __syncthreads();

  f32x4 a2[4][2];
  #pragma unroll
  for (int mt = 0; mt < 4; ++mt)
    #pragma unroll
    for (int nt = 0; nt < 2; ++nt) a2[mt][nt] = (f32x4){0.f,0.f,0.f,0.f};
  #pragma unroll
  for (int ks = 0; ks < 16; ++ks){
    s16x8 a[4];
    #pragma unroll
    for (int mt = 0; mt < 4; ++mt) a[mt] = *(const s16x8*)(hl + (mt*16+ks)*512 + lane*8);
    #pragma unroll
    for (int nt = 0; nt < 2; ++nt){
      s16x8 bq = *(const s16x8*)(fc2p + (((wv*2+nt)*16 + ks)*64 + lane)*8);
      #pragma unroll
      for (int mt = 0; mt < 4; ++mt) a2[mt][nt] = mfma_(a[mt], bq, a2[mt][nt]);
    }
  }
  #pragma unroll
  for (int mt = 0; mt < 4; ++mt)
    #pragma unroll
    for (int nt = 0; nt < 2; ++nt)
      #pragma unroll
      for (int j = 0; j < 4; ++j){
        const int b_  = mt*16 + r0 + j;
        const int col = wv*32 + nt*16 + c15;
        out[((size_t)b_*1024 + t)*128 + col] = a2[mt][nt][j];
      }
}

// ---------------------------------------------------------------------------
// packing kernels (unchanged)
// ---------------------------------------------------------------------------
__global__ void pack_w(const float* __restrict__ src1, int K1,
                       const float* __restrict__ src2, int K2,
                       int N, short* __restrict__ dst)
{
  const int KS = (K1 + K2) >> 5;
  const int total = (N >> 4) * KS * 64;
  const int tid = blockIdx.x*256 + threadIdx.x;
  if (tid >= total) return;
  const int lane = tid & 63;
  const int rest = tid >> 6;
  const int ks = rest % KS;
  const int ntile = rest / KS;
  const int n = ntile*16 + (lane & 15);
  const int k = ks*32 + ((lane >> 4) << 3);
  const float* s; int kk, stride;
  if (k < K1){ s = src1; kk = k;      stride = K1; }
  else       { s = src2; kk = k - K1; stride = K2; }
  const float4 f0 = *(const float4*)(s + n*stride + kk);
  const float4 f1 = *(const float4*)(s + n*stride + kk + 4);
  s16x8 r;
  r[0] = (short)bf16rne(f0.x); r[1] = (short)bf16rne(f0.y);
  r[2] = (short)bf16rne(f0.z); r[3] = (short)bf16rne(f0.w);
  r[4] = (short)bf16rne(f1.x); r[5] = (short)bf16rne(f1.y);
  r[6] = (short)bf16rne(f1.z); r[7] = (short)bf16rne(f1.w);
  *(s16x8*)(dst + tid*8) = r;
}

__global__ void pack_x_k(const float* __restrict__ x, short* __restrict__ xp){
  const int tid = blockIdx.x*256 + threadIdx.x;
  const int lane = tid & 63;
  const int ks = (tid >> 6) & 3;
  const int bg = (tid >> 8) & 3;
  const int t  = tid >> 10;
  const int b  = bg*16 + (lane & 15);
  const int k  = ks*32 + ((lane >> 4) << 3);
  const float* s = x + (b*1024 + t)*128 + k;
  const float4 f0 = *(const float4*)s;
  const float4 f1 = *(const float4*)(s + 4);
  s16x8 r;
  r[0] = (short)bf16rne(f0.x); r[1] = (short)bf16rne(f0.y);
  r[2] = (short)bf16rne(f0.z); r[3] = (short)bf16rne(f0.w);
  r[4] = (short)bf16rne(f1.x); r[5] = (short)bf16rne(f1.y);
  r[6] = (short)bf16rne(f1.z); r[7] = (short)bf16rne(f1.w);
  *(s16x8*)(xp + (size_t)tid*8) = r;
}

__global__ void addv(const float* __restrict__ a, const float* __restrict__ b,
                     float* __restrict__ o, int n){
  const int i = blockIdx.x*256 + threadIdx.x;
  if (i < n) o[i] = a[i] + b[i];
}

// ---------------------------------------------------------------------------
extern "C" void kernel_launch(void* const* d_in, const int* in_sizes, int n_in,
                              void* d_out, int out_size, void* d_ws, size_t ws_size,
                              hipStream_t stream)
{
  (void)in_sizes; (void)n_in; (void)out_size; (void)ws_size;
  const float* x     = (const float*)d_in[0];
  const float* eWih1 = (const float*)d_in[1];
  const float* eWhh1 = (const float*)d_in[2];
  const float* ebih1 = (const float*)d_in[3];
  const float* ebhh1 = (const float*)d_in[4];
  const float* eWih2 = (const float*)d_in[5];
  const float* eWhh2 = (const float*)d_in[6];
  const float* ebih2 = (const float*)d_in[7];
  const float* ebhh2 = (const float*)d_in[8];
  const float* dWih1 = (const float*)d_in[9];
  const float* dWhh1 = (const float*)d_in[10];
  const float* dbih1 = (const float*)d_in[11];
  const float* dbhh1 = (const float*)d_in[12];
  const float* dWih2 = (const float*)d_in[13];
  const float* dWhh2 = (const float*)d_in[14];
  const float* dbih2 = (const float*)d_in[15];
  const float* dbhh2 = (const float*)d_in[16];
  const float* fc1w  = (const float*)d_in[17];
  const float* fc1b  = (const float*)d_in[18];
  const float* fc2w  = (const float*)d_in[19];
  float* out = (float*)d_out;
  char* ws = (char*)d_ws;

  size_t off = 0;
  auto alloc = [&](size_t bytes){ size_t o = off; off += (bytes + 255) & ~(size_t)255; return o; };
  const size_t ENC1P = alloc(128*20*512*2);
  const size_t ENC2P = alloc(64*24*512*2);
  const size_t DEC1P = alloc(128*24*512*2);
  const size_t DEC2P = alloc(64*24*512*2);
  const size_t FC1P  = alloc(32*8*512*2);
  const size_t FC2P  = alloc(8*16*512*2);
  const size_t BC1E  = alloc(2048*4);
  const size_t BC2E  = alloc(1024*4);
  const size_t BC1D  = alloc(2048*4);
  const size_t BC2D  = alloc(1024*4);
  const size_t XP    = alloc((size_t)1024*4*4*512*2);
  const size_t ZFRAG = alloc((size_t)1025*4*8*512*2);
  const size_t DFRAG = alloc((size_t)1025*4*8*512*2);
  const size_t H1E   = alloc(2*4*16*512*2);
  const size_t H1D   = alloc(2*4*16*512*2);
  const size_t BAR   = alloc(8192);
  const size_t PRB   = alloc(8*16384);

  short* enc1p = (short*)(ws + ENC1P);
  short* enc2p = (short*)(ws + ENC2P);
  short* dec1p = (short*)(ws + DEC1P);
  short* dec2p = (short*)(ws + DEC2P);
  short* fc1p  = (short*)(ws + FC1P);
  short* fc2p  = (short*)(ws + FC2P);
  float* bc1e  = (float*)(ws + BC1E);
  float* bc2e  = (float*)(ws + BC2E);
  float* bc1d  = (float*)(ws + BC1D);
  float* bc2d  = (float*)(ws + BC2D);
  short* xp    = (short*)(ws + XP);
  short* zfrag = (short*)(ws + ZFRAG);
  short* dfrag = (short*)(ws + DFRAG);
  short* h1e   = (short*)(ws + H1E);
  short* h1d   = (short*)(ws + H1D);
  u32*   bar   = (u32*)(ws + BAR);
  u32*   prb   = (u32*)(ws + PRB);

  hipMemsetAsync(zfrag, 0, 4*8*512*2, stream);          // z slot 0 (h2 state t=0)
  hipMemsetAsync(dfrag, 0, 4*8*512*2, stream);
  hipMemsetAsync(h1e, 0, 2*4*16*512*2, stream);
  hipMemsetAsync(h1d, 0, 2*4*16*512*2, stream);
  hipMemsetAsync(bar, 0, 8192, stream);                 // all flag lines

  pack_w<<<640, 256, 0, stream>>>(eWih1, 128, eWhh1, 512, 2048, enc1p);
  pack_w<<<384, 256, 0, stream>>>(eWih2, 512, eWhh2, 256, 1024, enc2p);
  pack_w<<<768, 256, 0, stream>>>(dWih1, 256, dWhh1, 512, 2048, dec1p);
  pack_w<<<384, 256, 0, stream>>>(dWih2, 512, dWhh2, 256, 1024, dec2p);
  pack_w<<<64,  256, 0, stream>>>(fc1w,  256, fc1w,  0,   512,  fc1p);
  pack_w<<<32,  256, 0, stream>>>(fc2w,  512, fc2w,  0,   128,  fc2p);
  addv<<<8, 256, 0, stream>>>(ebih1, ebhh1, bc1e, 2048);
  addv<<<4, 256, 0, stream>>>(ebih2, ebhh2, bc2e, 1024);
  addv<<<8, 256, 0, stream>>>(dbih1, dbhh1, bc1d, 2048);
  addv<<<4, 256, 0, stream>>>(dbih2, dbhh2, bc2d, 1024);
  pack_x_k<<<4096, 256, 0, stream>>>(x, xp);

  scan2<<<128, 256, 0, stream>>>(xp, zfrag, dfrag, h1e, h1d,
                                 enc1p, enc2p, dec1p, dec2p,
                                 bc1e, bc2e, bc1d, bc2d, bar, prb);
  fc_kernel<<<1024, 256, 0, stream>>>(dfrag, fc1p, fc2p, fc1b, out);
}

// Round 11
// 3454.266 us; speedup vs baseline: 1.4506x; 1.2627x over previous
//
#include <hip/hip_runtime.h>
#include <stdint.h>

typedef __attribute__((ext_vector_type(8))) short s16x8;
typedef __attribute__((ext_vector_type(4))) float f32x4;
typedef __attribute__((ext_vector_type(16))) int i32x16;
typedef uint32_t u32;

#define DEV static __device__ __forceinline__

constexpr int T_ = 1024;

DEV u32 bf16rne(float x){
  u32 u = __float_as_uint(x);
  u = (u + 0x7FFFu + ((u >> 16) & 1u)) >> 16;
  return u;
}
DEV float sigm_(float x){ return 1.f / (1.f + __expf(-x)); }
DEV float tanh_(float x){
  float ax = fabsf(x);
  float e = __expf(-2.f * ax);
  float r = (1.f - e) / (1.f + e);
  return x < 0.f ? -r : r;
}
DEV f32x4 mfma_(s16x8 a, s16x8 b, f32x4 c){
  return __builtin_amdgcn_mfma_f32_16x16x32_bf16(a, b, c, 0, 0, 0);
}
DEV void wait_vm0(){ asm volatile("s_waitcnt vmcnt(0)" ::: "memory"); }
DEV void pin_v(s16x8 &x){ asm volatile("" : "+v"(x)); }

// ---- LLC-coherent primitives (sc0 sc1 — proven r2-r10) ---------------------
DEV s16x8 ldg_cc16(const short* p){
  s16x8 v; asm volatile("global_load_dwordx4 %0, %1, off sc0 sc1" : "=v"(v) : "v"(p) : "memory"); return v;
}
DEV void stg_cc2(short* p, u32 v){
  asm volatile("global_store_short %0, %1, off sc0 sc1" :: "v"(p), "v"(v) : "memory");
}
DEV void stflag_llc(u32* p, u32 v){
  asm volatile("global_store_dword %0, %1, off sc0 sc1" :: "v"(p), "v"(v) : "memory");
}
DEV u32 ldflag_wait_llc(const u32* p){
  u32 v; asm volatile("global_load_dword %0, %1, off sc0 sc1\ns_waitcnt vmcnt(0)" : "=v"(v) : "v"(p) : "memory");
  return v;
}
// ---- XCD-local (sc0-only) primitives — used ONLY after probe validation ----
DEV s16x8 ld16_x(const short* p){
  s16x8 v; asm volatile("global_load_dwordx4 %0, %1, off sc0" : "=v"(v) : "v"(p) : "memory"); return v;
}
DEV void st4_x(short* p, u32 v){
  asm volatile("global_store_dword %0, %1, off sc0" :: "v"(p), "v"(v) : "memory");
}
DEV void st2_x(short* p, u32 v){
  asm volatile("global_store_short %0, %1, off sc0" :: "v"(p), "v"(v) : "memory");
}
DEV void stflag_x(u32* p, u32 v){
  asm volatile("global_store_dword %0, %1, off sc0" :: "v"(p), "v"(v) : "memory");
}
DEV u32 ldflag_wait_x(const u32* p){
  u32 v; asm volatile("global_load_dword %0, %1, off sc0\ns_waitcnt vmcnt(0)" : "=v"(v) : "v"(p) : "memory");
  return v;
}
DEV void stprobe(u32* p, u32 v){
  asm volatile("global_store_dword %0, %1, off sc0" :: "v"(p), "v"(v) : "memory");
}
DEV u32 ldprobe(const u32* p){
  u32 v; asm volatile("global_load_dword %0, %1, off sc0\ns_waitcnt vmcnt(0)" : "=v"(v) : "v"(p) : "memory");
  return v;
}
// dual-path data helpers (fast is wave-uniform)
DEV s16x8 ld16f(bool fast, const short* p){ return fast ? ld16_x(p) : ldg_cc16(p); }
DEV void st4f(bool fast, short* p, u32 v){
  if (fast) st4_x(p, v);
  else asm volatile("global_store_dword %0, %1, off sc0 sc1" :: "v"(p), "v"(v) : "memory");
}
DEV void st2f(bool fast, short* p, u32 v){ if (fast) st2_x(p, v); else stg_cc2(p, v); }

// ---- explicit-AGPR weight residency (r6, proven) ---------------------------
#define LDW(R, ADDR) asm volatile("global_load_dwordx4 " R ", %0, off" :: "v"(ADDR))
#define MFMA_A(ACC, AF, R) \
  asm volatile("v_mfma_f32_16x16x32_bf16 %0, %1, " R ", %0" : "+v"(ACC) : "v"(AF))
#define MFMA_V(ACC, AF, BV) \
  asm volatile("v_mfma_f32_16x16x32_bf16 %0, %1, %2, %0" : "+v"(ACC) : "v"(AF), "v"(BV))
#define MFMA_AZ(D, AF, R, Z) \
  asm volatile("v_mfma_f32_16x16x32_bf16 %0, %1, " R ", %2" : "=&v"(D) : "v"(AF), "v"(Z))
#define POST_NOPS() asm volatile("s_nop 7\ns_nop 7\ns_nop 1") // MFMA D -> VALU read
#define LD8(V, P) V = *(const s16x8*)((P) + lane*8)

// LLC flag-line barrier (r9, proven). flags: [0..15]
template<int NOUT>
DEV void groupbar_llc(u32* flags, int w, u32 target, int tid){
  if constexpr (NOUT == 0)      asm volatile("s_waitcnt vmcnt(0)" ::: "memory");
  else if constexpr (NOUT == 1) asm volatile("s_waitcnt vmcnt(1)" ::: "memory");
  else                          asm volatile("s_waitcnt vmcnt(2)" ::: "memory");
  __syncthreads();
  if (tid == 0) stflag_llc(flags + w, target);
  if (tid < 64){
    const u32* p = flags + (tid & 15);
    while (true){
      u32 v = ldflag_wait_llc(p);
      if (__all((int)(v >= target))) break;
      __builtin_amdgcn_s_sleep(1);
    }
  }
  __syncthreads();
}

// dual-mode barrier (r10, proven). [0..15] primary, [16..31] LLC twin.
template<int NOUT>
DEV void groupbar2(bool fast, u32* flags, u32* encf, int w, u32 target, int tid){
  if constexpr (NOUT == 0)      asm volatile("s_waitcnt vmcnt(0)" ::: "memory");
  else if constexpr (NOUT == 1) asm volatile("s_waitcnt vmcnt(1)" ::: "memory");
  else                          asm volatile("s_waitcnt vmcnt(2)" ::: "memory");
  __syncthreads();
  if (tid == 0){
    if (encf) stflag_llc(encf + w, target);
    if (fast){ stflag_x(flags + w, target); stflag_llc(flags + 16 + w, target); }
    else stflag_llc(flags + w, target);
  }
  if (tid < 64){
    if (fast){
      const u32* p  = flags + (tid & 15);
      const u32* p2 = flags + 16 + (tid & 15);
      u32 it = 0;
      while (true){
        u32 v = ldflag_wait_x(p);
        if (__all((int)(v >= target))) break;
        if (((++it) & 511u) == 0u){
          u32 v2 = ldflag_wait_llc(p2);
          if (__all((int)(v2 >= target))) break;
        }
      }
    } else {
      const u32* p = flags + (tid & 15);
      while (true){
        u32 v = ldflag_wait_llc(p);
        if (__all((int)(v >= target))) break;
        __builtin_amdgcn_s_sleep(1);
      }
    }
  }
  __syncthreads();
}

// decoder waits for encoder progress with a MONOTONE per-thread snapshot:
// in steady state (enc far ahead) this is ZERO memory traffic and no sync.
DEV void wait_enc2(const u32* flags, u32 target, int tid, u32 &snap){
  if (__all((int)(snap >= target))) return;
  const u32* p = flags + (tid & 15);
  while (true){
    u32 v = ldflag_wait_llc(p);
    if (__all((int)(v >= target))){ snap = v; break; }
    __builtin_amdgcn_s_sleep(1);
  }
}

// ---------------------------------------------------------------------------
// XCD-coherence probe (r10, proven)
// ---------------------------------------------------------------------------
DEV bool probe_xcd(u32* prb, u32* pbf, u32* okf, int w, int tid, int* sscr){
  bool ok = true;
  #pragma unroll 1
  for (int round = 0; round < 2; ++round){
    const u32 salt = round ? 0xA5A5A5A5u : 0x5A5A5A5Au;
    u32 val = salt ^ ((u32)w << 20) ^ ((u32)tid * 2654435761u);
    stprobe(prb + w*256 + tid, val);
    groupbar_llc<0>(pbf, w, (u32)(round*2 + 1), tid);
    #pragma unroll 1
    for (int s = 0; s < 16; ++s){
      u32 exp = salt ^ ((u32)s << 20) ^ ((u32)tid * 2654435761u);
      u32 got = ldprobe(prb + s*256 + tid);
      ok &= (got == exp);
    }
    groupbar_llc<0>(pbf, w, (u32)(round*2 + 2), tid);
  }
  unsigned long long b = __ballot(ok);
  if ((tid & 63) == 0) sscr[tid >> 6] = (b == ~0ull) ? 1 : 0;
  __syncthreads();
  const int wgok = sscr[0] & sscr[1] & sscr[2] & sscr[3];
  __syncthreads();
  if (tid == 0) stflag_llc(okf + w, (u32)(1 + wgok));
  int fastv = 0;
  if (tid < 64){
    const u32* p = okf + (tid & 15);
    u32 v = 0;
    while (true){
      v = ldflag_wait_llc(p);
      if (__all((int)(v >= 1u))) break;
      __builtin_amdgcn_s_sleep(1);
    }
    fastv = __all((int)(v == 2u)) ? 1 : 0;
  }
  __syncthreads();
  if (tid == 0) sscr[4] = fastv;
  __syncthreads();
  return sscr[4] != 0;
}

// ---------------------------------------------------------------------------
// Fused 2-cell LSTM scan (r10 dataflow). MFMA clusters are software-pipelined:
// 4-fragment LDS load groups alternate with 8-MFMA groups, next group's loads
// issued BEFORE current group's asm MFMAs (loads overlap under lgkmcnt).
// ---------------------------------------------------------------------------
template<int KXB, bool DEC>
DEV void run_scan(const short* __restrict__ xsrc,  // [T][4][KXB][512]
                  short* __restrict__ seq,         // [T+1][4][8][512]
                  short* __restrict__ h1f,         // [2][4][16][512]
                  const short* __restrict__ w1p,
                  const short* __restrict__ w2p,
                  const float* __restrict__ bc1,
                  const float* __restrict__ bc2,
                  u32* mybar, u32* encf, bool fast,
                  int bg, int w,
                  short* lx, short* lh1, short* lh2,
                  float* g1, float* g2, float* c1s, float* c2s,
                  float* b1s, float* b2s)
{
  constexpr int KS1 = KXB + 16;
  constexpr int XB  = KXB/4;
  const int tid  = threadIdx.x;
  const int wv   = tid >> 6;
  const int lane = tid & 63;

  // ---- reserve the ENTIRE AGPR file (forces .agpr_count=256) ----
  i32x16 ag0,ag1,ag2,ag3,ag4,ag5,ag6,ag7,ag8,ag9,ag10,ag11,ag12,ag13,ag14,ag15;
  asm volatile("" : "=a"(ag0),"=a"(ag1),"=a"(ag2),"=a"(ag3),
                    "=a"(ag4),"=a"(ag5),"=a"(ag6),"=a"(ag7));
  asm volatile("" : "=a"(ag8),"=a"(ag9),"=a"(ag10),"=a"(ag11),
                    "=a"(ag12),"=a"(ag13),"=a"(ag14),"=a"(ag15));

  for (int i = tid; i < 16*32; i += 256) c1s[i] = 0.f;
  for (int i = tid; i < 16*16; i += 256) c2s[i] = 0.f;
  if (tid < 128) b1s[tid] = bc1[(tid>>5)*512 + w*32 + (tid&31)];
  if (tid < 64)  b2s[tid] = bc2[(tid>>4)*256 + w*16 + (tid&15)];

  // ---- weights -> architectural AGPRs (one-time, r6 verbatim) ----
  const int nt0 = wv*32 + w*2;
  const int nt2 = wv*16 + w;
  s16x8 W2v[8];                 // dec-only tail (32 VGPRs)
  {
    const short* b0 = w1p + (size_t)(nt0  )*KS1*512 + lane*8;
    const short* b1 = w1p + (size_t)(nt0+1)*KS1*512 + lane*8;
    const short* b2 = w2p + (size_t)nt2*24*512 + lane*8;
    if constexpr (!DEC){
      LDW("a[0:3]",   b0+0*512);  LDW("a[4:7]",   b0+1*512);  LDW("a[8:11]",  b0+2*512);  LDW("a[12:15]", b0+3*512);
      LDW("a[16:19]", b0+4*512);  LDW("a[20:23]", b0+5*512);  LDW("a[24:27]", b0+6*512);  LDW("a[28:31]", b0+7*512);
      LDW("a[32:35]", b0+8*512);  LDW("a[36:39]", b0+9*512);  LDW("a[40:43]", b0+10*512); LDW("a[44:47]", b0+11*512);
      LDW("a[48:51]", b0+12*512); LDW("a[52:55]", b0+13*512); LDW("a[56:59]", b0+14*512); LDW("a[60:63]", b0+15*512);
      LDW("a[64:67]", b0+16*512); LDW("a[68:71]", b0+17*512); LDW("a[72:75]", b0+18*512); LDW("a[76:79]", b0+19*512);
      LDW("a[80:83]",  b1+0*512);  LDW("a[84:87]",  b1+1*512);  LDW("a[88:91]",  b1+2*512);  LDW("a[92:95]",  b1+3*512);
      LDW("a[96:99]",  b1+4*512);  LDW("a[100:103]",b1+5*512);  LDW("a[104:107]",b1+6*512);  LDW("a[108:111]",b1+7*512);
      LDW("a[112:115]",b1+8*512);  LDW("a[116:119]",b1+9*512);  LDW("a[120:123]",b1+10*512); LDW("a[124:127]",b1+11*512);
      LDW("a[128:131]",b1+12*512); LDW("a[132:135]",b1+13*512); LDW("a[136:139]",b1+14*512); LDW("a[140:143]",b1+15*512);
      LDW("a[144:147]",b1+16*512); LDW("a[148:151]",b1+17*512); LDW("a[152:155]",b1+18*512); LDW("a[156:159]",b1+19*512);
      LDW("a[160:163]",b2+0*512);  LDW("a[164:167]",b2+1*512);  LDW("a[168:171]",b2+2*512);  LDW("a[172:175]",b2+3*512);
      LDW("a[176:179]",b2+4*512);  LDW("a[180:183]",b2+5*512);  LDW("a[184:187]",b2+6*512);  LDW("a[188:191]",b2+7*512);
      LDW("a[192:195]",b2+8*512);  LDW("a[196:199]",b2+9*512);  LDW("a[200:203]",b2+10*512); LDW("a[204:207]",b2+11*512);
      LDW("a[208:211]",b2+12*512); LDW("a[212:215]",b2+13*512); LDW("a[216:219]",b2+14*512); LDW("a[220:223]",b2+15*512);
      LDW("a[224:227]",b2+16*512); LDW("a[228:231]",b2+17*512); LDW("a[232:235]",b2+18*512); LDW("a[236:239]",b2+19*512);
      LDW("a[240:243]",b2+20*512); LDW("a[244:247]",b2+21*512); LDW("a[248:251]",b2+22*512); LDW("a[252:255]",b2+23*512);
    } else {
      LDW("a[0:3]",   b0+0*512);  LDW("a[4:7]",   b0+1*512);  LDW("a[8:11]",  b0+2*512);  LDW("a[12:15]", b0+3*512);
      LDW("a[16:19]", b0+4*512);  LDW("a[20:23]", b0+5*512);  LDW("a[24:27]", b0+6*512);  LDW("a[28:31]", b0+7*512);
      LDW("a[32:35]", b0+8*512);  LDW("a[36:39]", b0+9*512);  LDW("a[40:43]", b0+10*512); LDW("a[44:47]", b0+11*512);
      LDW("a[48:51]", b0+12*512); LDW("a[52:55]", b0+13*512); LDW("a[56:59]", b0+14*512); LDW("a[60:63]", b0+15*512);
      LDW("a[64:67]", b0+16*512); LDW("a[68:71]", b0+17*512); LDW("a[72:75]", b0+18*512); LDW("a[76:79]", b0+19*512);
      LDW("a[80:83]", b0+20*512); LDW("a[84:87]", b0+21*512); LDW("a[88:91]", b0+22*512); LDW("a[92:95]", b0+23*512);
      LDW("a[96:99]",  b1+0*512);  LDW("a[100:103]",b1+1*512);  LDW("a[104:107]",b1+2*512);  LDW("a[108:111]",b1+3*512);
      LDW("a[112:115]",b1+4*512);  LDW("a[116:119]",b1+5*512);  LDW("a[120:123]",b1+6*512);  LDW("a[124:127]",b1+7*512);
      LDW("a[128:131]",b1+8*512);  LDW("a[132:135]",b1+9*512);  LDW("a[136:139]",b1+10*512); LDW("a[140:143]",b1+11*512);
      LDW("a[144:147]",b1+12*512); LDW("a[148:151]",b1+13*512); LDW("a[152:155]",b1+14*512); LDW("a[156:159]",b1+15*512);
      LDW("a[160:163]",b1+16*512); LDW("a[164:167]",b1+17*512); LDW("a[168:171]",b1+18*512); LDW("a[172:175]",b1+19*512);
      LDW("a[176:179]",b1+20*512); LDW("a[180:183]",b1+21*512); LDW("a[184:187]",b1+22*512); LDW("a[188:191]",b1+23*512);
      LDW("a[192:195]",b2+0*512);  LDW("a[196:199]",b2+1*512);  LDW("a[200:203]",b2+2*512);  LDW("a[204:207]",b2+3*512);
      LDW("a[208:211]",b2+4*512);  LDW("a[212:215]",b2+5*512);  LDW("a[216:219]",b2+6*512);  LDW("a[220:223]",b2+7*512);
      LDW("a[224:227]",b2+8*512);  LDW("a[228:231]",b2+9*512);  LDW("a[232:235]",b2+10*512); LDW("a[236:239]",b2+11*512);
      LDW("a[240:243]",b2+12*512); LDW("a[244:247]",b2+13*512); LDW("a[248:251]",b2+14*512); LDW("a[252:255]",b2+15*512);
      #pragma unroll
      for (int i = 0; i < 8; ++i){
        W2v[i] = *(const s16x8*)(b2 + (16+i)*512);
        pin_v(W2v[i]);
      }
    }
    asm volatile("s_waitcnt vmcnt(0)" ::: "memory");
  }

  // persistent zero C-operand
  f32x4 zz = {0.f,0.f,0.f,0.f};
  asm volatile("" : "+v"(zz));

  u32 encSnap = 0;   // dec: monotone snapshot of enc progress flags

  // ---- prologue: stage h1_{-1} (zeros, parity 1) and x_0 ----
  {
    const short* h1src = h1f + (1*4 + bg)*16*512 + lane*8;
    s16x8 bh1[4];
    #pragma unroll
    for (int c = 0; c < 4; ++c) bh1[c] = ldg_cc16(h1src + (c*4+wv)*512);
    if constexpr (DEC) wait_enc2(encf, 2u, tid, encSnap);   // z_0 drained
    const short* xs = xsrc + (0*4 + bg)*KXB*512 + lane*8;
    s16x8 bx[XB];
    #pragma unroll
    for (int c = 0; c < XB; ++c)
      bx[c] = DEC ? ldg_cc16(xs + (c*4+wv)*512)
                  : *(const s16x8*)(xs + (c*4+wv)*512);
    wait_vm0();
    #pragma unroll
    for (int c = 0; c < 4; ++c) *(s16x8*)(lh1 + (c*4+wv)*512 + lane*8) = bh1[c];
    #pragma unroll
    for (int c = 0; c < XB; ++c) *(s16x8*)(lx + (c*4+wv)*512 + lane*8) = bx[c];
  }
  __syncthreads();

  for (int t = 0; t < T_; ++t){
    // ---- cell1: software-pipelined load/MFMA groups ----
    f32x4 a0a, a0b, a1a, a1b;
    {
      s16x8 p0,p1,p2,p3,q0,q1,q2,q3;
      if constexpr (!DEC){
        LD8(p0, lx +0*512); LD8(p1, lx +1*512); LD8(p2, lx +2*512); LD8(p3, lx +3*512);
        LD8(q0, lh1+0*512); LD8(q1, lh1+1*512); LD8(q2, lh1+2*512); LD8(q3, lh1+3*512);
        MFMA_AZ(a0a,p0,"a[0:3]",zz);   MFMA_AZ(a1a,p0,"a[80:83]",zz);
        MFMA_AZ(a0b,p1,"a[4:7]",zz);   MFMA_AZ(a1b,p1,"a[84:87]",zz);
        MFMA_A (a0a,p2,"a[8:11]");     MFMA_A (a1a,p2,"a[88:91]");
        MFMA_A (a0b,p3,"a[12:15]");    MFMA_A (a1b,p3,"a[92:95]");
        LD8(p0, lh1+4*512); LD8(p1, lh1+5*512); LD8(p2, lh1+6*512); LD8(p3, lh1+7*512);
        MFMA_A(a0a,q0,"a[16:19]"); MFMA_A(a1a,q0,"a[96:99]");
        MFMA_A(a0b,q1,"a[20:23]"); MFMA_A(a1b,q1,"a[100:103]");
        MFMA_A(a0a,q2,"a[24:27]"); MFMA_A(a1a,q2,"a[104:107]");
        MFMA_A(a0b,q3,"a[28:31]"); MFMA_A(a1b,q3,"a[108:111]");
        LD8(q0, lh1+8*512); LD8(q1, lh1+9*512); LD8(q2, lh1+10*512); LD8(q3, lh1+11*512);
        MFMA_A(a0a,p0,"a[32:35]"); MFMA_A(a1a,p0,"a[112:115]");
        MFMA_A(a0b,p1,"a[36:39]"); MFMA_A(a1b,p1,"a[116:119]");
        MFMA_A(a0a,p2,"a[40:43]"); MFMA_A(a1a,p2,"a[120:123]");
        MFMA_A(a0b,p3,"a[44:47]"); MFMA_A(a1b,p3,"a[124:127]");
        LD8(p0, lh1+12*512); LD8(p1, lh1+13*512); LD8(p2, lh1+14*512); LD8(p3, lh1+15*512);
        MFMA_A(a0a,q0,"a[48:51]"); MFMA_A(a1a,q0,"a[128:131]");
        MFMA_A(a0b,q1,"a[52:55]"); MFMA_A(a1b,q1,"a[132:135]");
        MFMA_A(a0a,q2,"a[56:59]"); MFMA_A(a1a,q2,"a[136:139]");
        MFMA_A(a0b,q3,"a[60:63]"); MFMA_A(a1b,q3,"a[140:143]");
        MFMA_A(a0a,p0,"a[64:67]"); MFMA_A(a1a,p0,"a[144:147]");
        MFMA_A(a0b,p1,"a[68:71]"); MFMA_A(a1b,p1,"a[148:151]");
        MFMA_A(a0a,p2,"a[72:75]"); MFMA_A(a1a,p2,"a[152:155]");
        MFMA_A(a0b,p3,"a[76:79]"); MFMA_A(a1b,p3,"a[156:159]");
      } else {
        LD8(p0, lx +0*512); LD8(p1, lx +1*512); LD8(p2, lx +2*512); LD8(p3, lx +3*512);
        LD8(q0, lx +4*512); LD8(q1, lx +5*512); LD8(q2, lx +6*512); LD8(q3, lx +7*512);
        MFMA_AZ(a0a,p0,"a[0:3]",zz);   MFMA_AZ(a1a,p0,"a[96:99]",zz);
        MFMA_AZ(a0b,p1,"a[4:7]",zz);   MFMA_AZ(a1b,p1,"a[100:103]",zz);
        MFMA_A (a0a,p2,"a[8:11]");     MFMA_A (a1a,p2,"a[104:107]");
        MFMA_A (a0b,p3,"a[12:15]");    MFMA_A (a1b,p3,"a[108:111]");
        LD8(p0, lh1+0*512); LD8(p1, lh1+1*512); LD8(p2, lh1+2*512); LD8(p3, lh1+3*512);
        MFMA_A(a0a,q0,"a[16:19]"); MFMA_A(a1a,q0,"a[112:115]");
        MFMA_A(a0b,q1,"a[20:23]"); MFMA_A(a1b,q1,"a[116:119]");
        MFMA_A(a0a,q2,"a[24:27]"); MFMA_A(a1a,q2,"a[120:123]");
        MFMA_A(a0b,q3,"a[28:31]"); MFMA_A(a1b,q3,"a[124:127]");
        LD8(q0, lh1+4*512); LD8(q1, lh1+5*512); LD8(q2, lh1+6*512); LD8(q3, lh1+7*512);
        MFMA_A(a0a,p0,"a[32:35]"); MFMA_A(a1a,p0,"a[128:131]");
        MFMA_A(a0b,p1,"a[36:39]"); MFMA_A(a1b,p1,"a[132:135]");
        MFMA_A(a0a,p2,"a[40:43]"); MFMA_A(a1a,p2,"a[136:139]");
        MFMA_A(a0b,p3,"a[44:47]"); MFMA_A(a1b,p3,"a[140:143]");
        LD8(p0, lh1+8*512); LD8(p1, lh1+9*512); LD8(p2, lh1+10*512); LD8(p3, lh1+11*512);
        MFMA_A(a0a,q0,"a[48:51]"); MFMA_A(a1a,q0,"a[144:147]");
        MFMA_A(a0b,q1,"a[52:55]"); MFMA_A(a1b,q1,"a[148:151]");
        MFMA_A(a0a,q2,"a[56:59]"); MFMA_A(a1a,q2,"a[152:155]");
        MFMA_A(a0b,q3,"a[60:63]"); MFMA_A(a1b,q3,"a[156:159]");
        LD8(q0, lh1+12*512); LD8(q1, lh1+13*512); LD8(q2, lh1+14*512); LD8(q3, lh1+15*512);
        MFMA_A(a0a,p0,"a[64:67]"); MFMA_A(a1a,p0,"a[160:163]");
        MFMA_A(a0b,p1,"a[68:71]"); MFMA_A(a1b,p1,"a[164:167]");
        MFMA_A(a0a,p2,"a[72:75]"); MFMA_A(a1a,p2,"a[168:171]");
        MFMA_A(a0b,p3,"a[76:79]"); MFMA_A(a1b,p3,"a[172:175]");
        MFMA_A(a0a,q0,"a[80:83]"); MFMA_A(a1a,q0,"a[176:179]");
        MFMA_A(a0b,q1,"a[84:87]"); MFMA_A(a1b,q1,"a[180:183]");
        MFMA_A(a0a,q2,"a[88:91]"); MFMA_A(a1a,q2,"a[184:187]");
        MFMA_A(a0b,q3,"a[92:95]"); MFMA_A(a1b,q3,"a[188:191]");
      }
    }
    POST_NOPS();
    {
      const f32x4 acc0 = a0a + a0b, acc1 = a1a + a1b;
      const int r0 = (lane>>4)*4, cc = lane & 15;
      #pragma unroll
      for (int j = 0; j < 4; ++j){
        g1[wv*528 + (r0+j)*33 + cc]      = acc0[j];
        g1[wv*528 + (r0+j)*33 + 16 + cc] = acc1[j];
      }
    }
    __syncthreads();

    // ---- elementwise: h1 slice ----
    {
      short* h1dst = h1f + (((t&1)*4 + bg)*16 + w)*512;
      const int idx = tid << 1;
      const int r = idx >> 5;
      const int c = idx & 31;
      float hv0 = 0.f, hv1 = 0.f;
      #pragma unroll
      for (int p = 0; p < 2; ++p){
        const int cp = c + p;
        const float xi = g1[0*528 + r*33+cp] + b1s[0*32+cp];
        const float xf = g1[1*528 + r*33+cp] + b1s[1*32+cp];
        const float xg = g1[2*528 + r*33+cp] + b1s[2*32+cp];
        const float xo = g1[3*528 + r*33+cp] + b1s[3*32+cp];
        const float ii = sigm_(xi), ff = sigm_(xf), oo = sigm_(xo);
        const float gg = tanh_(xg);
        const float cn = ff * c1s[r*32+cp] + ii * gg;
        c1s[r*32+cp] = cn;
        const float hv = oo * tanh_(cn);
        if (p == 0) hv0 = hv; else hv1 = hv;
      }
      const u32 pk = bf16rne(hv0) | (bf16rne(hv1) << 16);
      st4f(fast, h1dst + ((((c>>3)<<4) + r) << 3) + (c & 7), pk);
    }

    // ---- enc-progress (cached snapshot) + next x/z prefetch ----
    const int tn = (t+1 < T_) ? (t+1) : (T_-1);
    if constexpr (DEC) wait_enc2(encf, (u32)(tn+2), tid, encSnap);
    s16x8 bx[XB];
    {
      const short* xs = xsrc + (tn*4 + bg)*KXB*512 + lane*8;
      #pragma unroll
      for (int c = 0; c < XB; ++c)
        bx[c] = DEC ? ldg_cc16(xs + (c*4+wv)*512)
                    : *(const s16x8*)(xs + (c*4+wv)*512);
    }

    groupbar2<XB>(fast, mybar, DEC ? nullptr : encf, w, (u32)(t+1), tid);

    // ---- stage: h1_t, h2_{t-1}; x from prefetch ----
    {
      const short* h1src = h1f + ((t&1)*4 + bg)*16*512 + lane*8;
      const short* h2src = seq + (t*4 + bg)*8*512 + lane*8;
      s16x8 bh1[4], bh2[2];
      #pragma unroll
      for (int c = 0; c < 4; ++c) bh1[c] = ld16f(fast, h1src + (c*4+wv)*512);
      #pragma unroll
      for (int c = 0; c < 2; ++c)
        bh2[c] = DEC ? ld16f(fast, h2src + (c*4+wv)*512)
                     : ldg_cc16(h2src + (c*4+wv)*512);
      wait_vm0();
      #pragma unroll
      for (int c = 0; c < 4; ++c) *(s16x8*)(lh1 + (c*4+wv)*512 + lane*8) = bh1[c];
      #pragma unroll
      for (int c = 0; c < 2; ++c) *(s16x8*)(lh2 + (c*4+wv)*512 + lane*8) = bh2[c];
      #pragma unroll
      for (int c = 0; c < XB; ++c) *(s16x8*)(lx + (c*4+wv)*512 + lane*8) = bx[c];
    }
    __syncthreads();

    // ---- cell2: software-pipelined load/MFMA groups ----
    f32x4 aca, acb;
    {
      s16x8 p0,p1,p2,p3,q0,q1,q2,q3;
      if constexpr (!DEC){
        LD8(p0, lh1+0*512); LD8(p1, lh1+1*512); LD8(p2, lh1+2*512); LD8(p3, lh1+3*512);
        LD8(q0, lh1+4*512); LD8(q1, lh1+5*512); LD8(q2, lh1+6*512); LD8(q3, lh1+7*512);
        MFMA_AZ(aca,p0,"a[160:163]",zz); MFMA_AZ(acb,p1,"a[164:167]",zz);
        MFMA_A (aca,p2,"a[168:171]");    MFMA_A (acb,p3,"a[172:175]");
        LD8(p0, lh1+8*512); LD8(p1, lh1+9*512); LD8(p2, lh1+10*512); LD8(p3, lh1+11*512);
        MFMA_A(aca,q0,"a[176:179]"); MFMA_A(acb,q1,"a[180:183]");
        MFMA_A(aca,q2,"a[184:187]"); MFMA_A(acb,q3,"a[188:191]");
        LD8(q0, lh1+12*512); LD8(q1, lh1+13*512); LD8(q2, lh1+14*512); LD8(q3, lh1+15*512);
        MFMA_A(aca,p0,"a[192:195]"); MFMA_A(acb,p1,"a[196:199]");
        MFMA_A(aca,p2,"a[200:203]"); MFMA_A(acb,p3,"a[204:207]");
        LD8(p0, lh2+0*512); LD8(p1, lh2+1*512); LD8(p2, lh2+2*512); LD8(p3, lh2+3*512);
        MFMA_A(aca,q0,"a[208:211]"); MFMA_A(acb,q1,"a[212:215]");
        MFMA_A(aca,q2,"a[216:219]"); MFMA_A(acb,q3,"a[220:223]");
        LD8(q0, lh2+4*512); LD8(q1, lh2+5*512); LD8(q2, lh2+6*512); LD8(q3, lh2+7*512);
        MFMA_A(aca,p0,"a[224:227]"); MFMA_A(acb,p1,"a[228:231]");
        MFMA_A(aca,p2,"a[232:235]"); MFMA_A(acb,p3,"a[236:239]");
        MFMA_A(aca,q0,"a[240:243]"); MFMA_A(acb,q1,"a[244:247]");
        MFMA_A(aca,q2,"a[248:251]"); MFMA_A(acb,q3,"a[252:255]");
      } else {
        LD8(p0, lh1+0*512); LD8(p1, lh1+1*512); LD8(p2, lh1+2*512); LD8(p3, lh1+3*512);
        LD8(q0, lh1+4*512); LD8(q1, lh1+5*512); LD8(q2, lh1+6*512); LD8(q3, lh1+7*512);
        MFMA_AZ(aca,p0,"a[192:195]",zz); MFMA_AZ(acb,p1,"a[196:199]",zz);
        MFMA_A (aca,p2,"a[200:203]");    MFMA_A (acb,p3,"a[204:207]");
        LD8(p0, lh1+8*512); LD8(p1, lh1+9*512); LD8(p2, lh1+10*512); LD8(p3, lh1+11*512);
        MFMA_A(aca,q0,"a[208:211]"); MFMA_A(acb,q1,"a[212:215]");
        MFMA_A(aca,q2,"a[216:219]"); MFMA_A(acb,q3,"a[220:223]");
        LD8(q0, lh1+12*512); LD8(q1, lh1+13*512); LD8(q2, lh1+14*512); LD8(q3, lh1+15*512);
        MFMA_A(aca,p0,"a[224:227]"); MFMA_A(acb,p1,"a[228:231]");
        MFMA_A(aca,p2,"a[232:235]"); MFMA_A(acb,p3,"a[236:239]");
        LD8(p0, lh2+0*512); LD8(p1, lh2+1*512); LD8(p2, lh2+2*512); LD8(p3, lh2+3*512);
        MFMA_A(aca,q0,"a[240:243]"); MFMA_A(acb,q1,"a[244:247]");
        MFMA_A(aca,q2,"a[248:251]"); MFMA_A(acb,q3,"a[252:255]");
        LD8(q0, lh2+4*512); LD8(q1, lh2+5*512); LD8(q2, lh2+6*512); LD8(q3, lh2+7*512);
        MFMA_V(aca,p0,W2v[0]); MFMA_V(acb,p1,W2v[1]);
        MFMA_V(aca,p2,W2v[2]); MFMA_V(acb,p3,W2v[3]);
        MFMA_V(aca,q0,W2v[4]); MFMA_V(acb,q1,W2v[5]);
        MFMA_V(aca,q2,W2v[6]); MFMA_V(acb,q3,W2v[7]);
      }
    }
    POST_NOPS();
    {
      const f32x4 acc = aca + acb;
      const int r0 = (lane>>4)*4, cc = lane & 15;
      #pragma unroll
      for (int j = 0; j < 4; ++j) g2[wv*272 + (r0+j)*17 + cc] = acc[j];
    }
    __syncthreads();
    {
      short* odst = seq + ((t+1)*4 + bg)*8*512;
      const int r = tid >> 4, c = tid & 15;
      const float xi = g2[0*272 + r*17+c] + b2s[0*16+c];
      const float xf = g2[1*272 + r*17+c] + b2s[1*16+c];
      const float xg = g2[2*272 + r*17+c] + b2s[2*16+c];
      const float xo = g2[3*272 + r*17+c] + b2s[3*16+c];
      const float ii = sigm_(xi), ff = sigm_(xf), oo = sigm_(xo);
      const float gg = tanh_(xg);
      const float cn = ff * c2s[r*16+c] + ii * gg;
      c2s[r*16+c] = cn;
      const float hv = oo * tanh_(cn);
      const int jj = ((w & 1) << 4) + c;
      const int off = (((w>>1)*64 + ((jj>>3)<<4) + r) << 3) + (jj & 7);
      if constexpr (DEC) st2f(fast, odst + off, bf16rne(hv));
      else stg_cc2(odst + off, bf16rne(hv));   // cross-group: dec reads via LLC
    }
  }

  if constexpr (!DEC){
    wait_vm0();
    __syncthreads();
    if (tid == 0) stflag_llc(encf + w, (u32)(T_+1));
  }

  asm volatile("" :: "a"(ag0),"a"(ag1),"a"(ag2),"a"(ag3),
                     "a"(ag4),"a"(ag5),"a"(ag6),"a"(ag7));
  asm volatile("" :: "a"(ag8),"a"(ag9),"a"(ag10),"a"(ag11),
                     "a"(ag12),"a"(ag13),"a"(ag14),"a"(ag15));
}

// group gg = blockIdx&7 (16 WGs, stride 8 -> one XCD under round-robin
// dispatch; verified by the probe, NOT assumed). gg 0..3 enc, 4..7 dec.
__launch_bounds__(256, 1)
__global__ void scan2(const short* __restrict__ xp,
                      short* __restrict__ zfrag, short* __restrict__ dfrag,
                      short* __restrict__ h1e, short* __restrict__ h1d,
                      const short* __restrict__ enc1p, const short* __restrict__ enc2p,
                      const short* __restrict__ dec1p, const short* __restrict__ dec2p,
                      const float* __restrict__ bc1e, const float* __restrict__ bc2e,
                      const float* __restrict__ bc1d, const float* __restrict__ bc2d,
                      u32* __restrict__ bar, u32* __restrict__ prb)
{
  __shared__ short lx[8*512];
  __shared__ short lh1[16*512];
  __shared__ short lh2[8*512];
  __shared__ float g1[4*528];
  __shared__ float g2[4*272];
  __shared__ float c1s[16*32];
  __shared__ float c2s[16*16];
  __shared__ float b1s[128];
  __shared__ float b2s[64];
  __shared__ int sscr[8];

  const int b  = blockIdx.x;
  const int gg = b & 7;
  const int w  = b >> 3;
  const bool isdec = (gg >= 4);
  const int bg = isdec ? (gg - 4) : gg;

  const bool fast = probe_xcd(prb + gg*4096, bar + 1024 + gg*16,
                              bar + 1280 + gg*16, w, threadIdx.x, sscr);

  u32* myflags = bar + gg*32;           // [0..15] primary, [16..31] LLC twin
  u32* encf    = bar + 512 + bg*16;     // enc progress (LLC, cross-group)

  if (!isdec){
    run_scan<4, false>(xp, zfrag, h1e, enc1p, enc2p, bc1e, bc2e,
                       myflags, encf, fast, bg, w,
                       lx, lh1, lh2, g1, g2, c1s, c2s, b1s, b2s);
  } else {
    run_scan<8, true>(zfrag + 4*8*512, dfrag, h1d, dec1p, dec2p, bc1d, bc2d,
                      myflags, encf, fast, bg, w,
                      lx, lh1, lh2, g1, g2, c1s, c2s, b1s, b2s);
  }
}

// ---------------------------------------------------------------------------
// fused fc1(relu)+fc2 over one t-slice (64 rows) per block  (unchanged)
// ---------------------------------------------------------------------------
__launch_bounds__(256, 1)
__global__ void fc_kernel(const short* __restrict__ dfrag,
                          const short* __restrict__ fc1p,
                          const short* __restrict__ fc2p,
                          const float* __restrict__ fc1b,
                          float* __restrict__ out)
{
  const int t = blockIdx.x;
  const int tid = threadIdx.x, wv = tid >> 6, lane = tid & 63;
  __shared__ short hl[4*16*512];
  const short* A = dfrag + (size_t)(t+1)*4*8*512;

  f32x4 acc[4][8];
  #pragma unroll
  for (int mt = 0; mt < 4; ++mt)
    #pragma unroll
    for (int nt = 0; nt < 8; ++nt) acc[mt][nt] = (f32x4){0.f,0.f,0.f,0.f};

  #pragma unroll
  for (int ks = 0; ks < 8; ++ks){
    s16x8 a[4];
    #pragma unroll
    for (int mt = 0; mt < 4; ++mt) a[mt] = *(const s16x8*)(A + (mt*8+ks)*512 + lane*8);
    #pragma unroll
    for (int nt = 0; nt < 8; ++nt){
      s16x8 bq = *(const s16x8*)(fc1p + (((wv*8+nt)*8 + ks)*64 + lane)*8);
      #pragma unroll
      for (int mt = 0; mt < 4; ++mt) acc[mt][nt] = mfma_(a[mt], bq, acc[mt][nt]);
    }
  }
  const int r0 = (lane>>4)*4, c15 = lane & 15;
  #pragma unroll
  for (int nt = 0; nt < 8; ++nt){
    const int col = wv*128 + nt*16 + c15;
    const float bia = fc1b[col];
    const int ks2 = col >> 5, lp = (((col & 31) >> 3) << 4), e = col & 7;
    #pragma unroll
    for (int mt = 0; mt < 4; ++mt)
      #pragma unroll
      for (int j = 0; j < 4; ++j){
        float v = acc[mt][nt][j] + bia;
        v = v > 0.f ? v : 0.f;
        hl[(mt*16 + ks2)*512 + (lp + r0 + j)*8 + e] = (short)bf16rne(v);
      }
  }
  __syncthreads();

  f32x4 a2[4][2];
  #pragma unroll
  for (int mt = 0; mt < 4; ++mt)
    #pragma unroll
    for (int nt = 0; nt < 2; ++nt) a2[mt][nt] = (f32x4){0.f,0.f,0.f,0.f};
  #pragma unroll
  for (int ks = 0; ks < 16; ++ks){
    s16x8 a[4];
    #pragma unroll
    for (int mt = 0; mt < 4; ++mt) a[mt] = *(const s16x8*)(hl + (mt*16+ks)*512 + lane*8);
    #pragma unroll
    for (int nt = 0; nt < 2; ++nt){
      s16x8 bq = *(const s16x8*)(fc2p + (((wv*2+nt)*16 + ks)*64 + lane)*8);
      #pragma unroll
      for (int mt = 0; mt < 4; ++mt) a2[mt][nt] = mfma_(a[mt], bq, a2[mt][nt]);
    }
  }
  #pragma unroll
  for (int mt = 0; mt < 4; ++mt)
    #pragma unroll
    for (int nt = 0; nt < 2; ++nt)
      #pragma unroll
      for (int j = 0; j < 4; ++j){
        const int b_  = mt*16 + r0 + j;
        const int col = wv*32 + nt*16 + c15;
        out[((size_t)b_*1024 + t)*128 + col] = a2[mt][nt][j];
      }
}

// ---------------------------------------------------------------------------
// packing kernels (unchanged)
// ---------------------------------------------------------------------------
__global__ void pack_w(const float* __restrict__ src1, int K1,
                       const float* __restrict__ src2, int K2,
                       int N, short* __restrict__ dst)
{
  const int KS = (K1 + K2) >> 5;
  const int total = (N >> 4) * KS * 64;
  const int tid = blockIdx.x*256 + threadIdx.x;
  if (tid >= total) return;
  const int lane = tid & 63;
  const int rest = tid >> 6;
  const int ks = rest % KS;
  const int ntile = rest / KS;
  const int n = ntile*16 + (lane & 15);
  const int k = ks*32 + ((lane >> 4) << 3);
  const float* s; int kk, stride;
  if (k < K1){ s = src1; kk = k;      stride = K1; }
  else       { s = src2; kk = k - K1; stride = K2; }
  const float4 f0 = *(const float4*)(s + n*stride + kk);
  const float4 f1 = *(const float4*)(s + n*stride + kk + 4);
  s16x8 r;
  r[0] = (short)bf16rne(f0.x); r[1] = (short)bf16rne(f0.y);
  r[2] = (short)bf16rne(f0.z); r[3] = (short)bf16rne(f0.w);
  r[4] = (short)bf16rne(f1.x); r[5] = (short)bf16rne(f1.y);
  r[6] = (short)bf16rne(f1.z); r[7] = (short)bf16rne(f1.w);
  *(s16x8*)(dst + tid*8) = r;
}

__global__ void pack_x_k(const float* __restrict__ x, short* __restrict__ xp){
  const int tid = blockIdx.x*256 + threadIdx.x;
  const int lane = tid & 63;
  const int ks = (tid >> 6) & 3;
  const int bg = (tid >> 8) & 3;
  const int t  = tid >> 10;
  const int b  = bg*16 + (lane & 15);
  const int k  = ks*32 + ((lane >> 4) << 3);
  const float* s = x + (b*1024 + t)*128 + k;
  const float4 f0 = *(const float4*)s;
  const float4 f1 = *(const float4*)(s + 4);
  s16x8 r;
  r[0] = (short)bf16rne(f0.x); r[1] = (short)bf16rne(f0.y);
  r[2] = (short)bf16rne(f0.z); r[3] = (short)bf16rne(f0.w);
  r[4] = (short)bf16rne(f1.x); r[5] = (short)bf16rne(f1.y);
  r[6] = (short)bf16rne(f1.z); r[7] = (short)bf16rne(f1.w);
  *(s16x8*)(xp + (size_t)tid*8) = r;
}

__global__ void addv(const float* __restrict__ a, const float* __restrict__ b,
                     float* __restrict__ o, int n){
  const int i = blockIdx.x*256 + threadIdx.x;
  if (i < n) o[i] = a[i] + b[i];
}

// ---------------------------------------------------------------------------
extern "C" void kernel_launch(void* const* d_in, const int* in_sizes, int n_in,
                              void* d_out, int out_size, void* d_ws, size_t ws_size,
                              hipStream_t stream)
{
  (void)in_sizes; (void)n_in; (void)out_size; (void)ws_size;
  const float* x     = (const float*)d_in[0];
  const float* eWih1 = (const float*)d_in[1];
  const float* eWhh1 = (const float*)d_in[2];
  const float* ebih1 = (const float*)d_in[3];
  const float* ebhh1 = (const float*)d_in[4];
  const float* eWih2 = (const float*)d_in[5];
  const float* eWhh2 = (const float*)d_in[6];
  const float* ebih2 = (const float*)d_in[7];
  const float* ebhh2 = (const float*)d_in[8];
  const float* dWih1 = (const float*)d_in[9];
  const float* dWhh1 = (const float*)d_in[10];
  const float* dbih1 = (const float*)d_in[11];
  const float* dbhh1 = (const float*)d_in[12];
  const float* dWih2 = (const float*)d_in[13];
  const float* dWhh2 = (const float*)d_in[14];
  const float* dbih2 = (const float*)d_in[15];
  const float* dbhh2 = (const float*)d_in[16];
  const float* fc1w  = (const float*)d_in[17];
  const float* fc1b  = (const float*)d_in[18];
  const float* fc2w  = (const float*)d_in[19];
  float* out = (float*)d_out;
  char* ws = (char*)d_ws;

  size_t off = 0;
  auto alloc = [&](size_t bytes){ size_t o = off; off += (bytes + 255) & ~(size_t)255; return o; };
  const size_t ENC1P = alloc(128*20*512*2);
  const size_t ENC2P = alloc(64*24*512*2);
  const size_t DEC1P = alloc(128*24*512*2);
  const size_t DEC2P = alloc(64*24*512*2);
  const size_t FC1P  = alloc(32*8*512*2);
  const size_t FC2P  = alloc(8*16*512*2);
  const size_t BC1E  = alloc(2048*4);
  const size_t BC2E  = alloc(1024*4);
  const size_t BC1D  = alloc(2048*4);
  const size_t BC2D  = alloc(1024*4);
  const size_t XP    = alloc((size_t)1024*4*4*512*2);
  const size_t ZFRAG = alloc((size_t)1025*4*8*512*2);
  const size_t DFRAG = alloc((size_t)1025*4*8*512*2);
  const size_t H1E   = alloc(2*4*16*512*2);
  const size_t H1D   = alloc(2*4*16*512*2);
  const size_t BAR   = alloc(8192);
  const size_t PRB   = alloc(8*16384);

  short* enc1p = (short*)(ws + ENC1P);
  short* enc2p = (short*)(ws + ENC2P);
  short* dec1p = (short*)(ws + DEC1P);
  short* dec2p = (short*)(ws + DEC2P);
  short* fc1p  = (short*)(ws + FC1P);
  short* fc2p  = (short*)(ws + FC2P);
  float* bc1e  = (float*)(ws + BC1E);
  float* bc2e  = (float*)(ws + BC2E);
  float* bc1d  = (float*)(ws + BC1D);
  float* bc2d  = (float*)(ws + BC2D);
  short* xp    = (short*)(ws + XP);
  short* zfrag = (short*)(ws + ZFRAG);
  short* dfrag = (short*)(ws + DFRAG);
  short* h1e   = (short*)(ws + H1E);
  short* h1d   = (short*)(ws + H1D);
  u32*   bar   = (u32*)(ws + BAR);
  u32*   prb   = (u32*)(ws + PRB);

  hipMemsetAsync(zfrag, 0, 4*8*512*2, stream);          // z slot 0 (h2 state t=0)
  hipMemsetAsync(dfrag, 0, 4*8*512*2, stream);
  hipMemsetAsync(h1e, 0, 2*4*16*512*2, stream);
  hipMemsetAsync(h1d, 0, 2*4*16*512*2, stream);
  hipMemsetAsync(bar, 0, 8192, stream);                 // all flag lines

  pack_w<<<640, 256, 0, stream>>>(eWih1, 128, eWhh1, 512, 2048, enc1p);
  pack_w<<<384, 256, 0, stream>>>(eWih2, 512, eWhh2, 256, 1024, enc2p);
  pack_w<<<768, 256, 0, stream>>>(dWih1, 256, dWhh1, 512, 2048, dec1p);
  pack_w<<<384, 256, 0, stream>>>(dWih2, 512, dWhh2, 256, 1024, dec2p);
  pack_w<<<64,  256, 0, stream>>>(fc1w,  256, fc1w,  0,   512,  fc1p);
  pack_w<<<32,  256, 0, stream>>>(fc2w,  512, fc2w,  0,   128,  fc2p);
  addv<<<8, 256, 0, stream>>>(ebih1, ebhh1, bc1e, 2048);
  addv<<<4, 256, 0, stream>>>(ebih2, ebhh2, bc2e, 1024);
  addv<<<8, 256, 0, stream>>>(dbih1, dbhh1, bc1d, 2048);
  addv<<<4, 256, 0, stream>>>(dbih2, dbhh2, bc2d, 1024);
  pack_x_k<<<4096, 256, 0, stream>>>(x, xp);

  scan2<<<128, 256, 0, stream>>>(xp, zfrag, dfrag, h1e, h1d,
                                 enc1p, enc2p, dec1p, dec2p,
                                 bc1e, bc2e, bc1d, bc2d, bar, prb);
  fc_kernel<<<1024, 256, 0, stream>>>(dfrag, fc1p, fc2p, fc1b, out);
}

// Round 13
// 3440.178 us; speedup vs baseline: 1.4565x; 1.0041x over previous
//
#include <hip/hip_runtime.h>
#include <stdint.h>

typedef __attribute__((ext_vector_type(8))) short s16x8;
typedef __attribute__((ext_vector_type(4))) float f32x4;
typedef __attribute__((ext_vector_type(16))) int i32x16;
typedef uint32_t u32;

#define DEV static __device__ __forceinline__

constexpr int T_ = 1024;

DEV u32 bf16rne(float x){
  u32 u = __float_as_uint(x);
  u = (u + 0x7FFFu + ((u >> 16) & 1u)) >> 16;
  return u;
}
DEV float sigm_(float x){ return 1.f / (1.f + __expf(-x)); }
DEV float tanh_(float x){
  float ax = fabsf(x);
  float e = __expf(-2.f * ax);
  float r = (1.f - e) / (1.f + e);
  return x < 0.f ? -r : r;
}
DEV f32x4 mfma_(s16x8 a, s16x8 b, f32x4 c){
  return __builtin_amdgcn_mfma_f32_16x16x32_bf16(a, b, c, 0, 0, 0);
}
DEV void wait_vm0(){ asm volatile("s_waitcnt vmcnt(0)" ::: "memory"); }
DEV void pin_v(s16x8 &x){ asm volatile("" : "+v"(x)); }

// ---- LLC-coherent primitives (sc0 sc1 — proven r2-r10) ---------------------
DEV s16x8 ldg_cc16(const short* p){
  s16x8 v; asm volatile("global_load_dwordx4 %0, %1, off sc0 sc1" : "=v"(v) : "v"(p) : "memory"); return v;
}
DEV void stg_cc2(short* p, u32 v){
  asm volatile("global_store_short %0, %1, off sc0 sc1" :: "v"(p), "v"(v) : "memory");
}
DEV void stflag_llc(u32* p, u32 v){
  asm volatile("global_store_dword %0, %1, off sc0 sc1" :: "v"(p), "v"(v) : "memory");
}
DEV u32 ldflag_wait_llc(const u32* p){
  u32 v; asm volatile("global_load_dword %0, %1, off sc0 sc1\ns_waitcnt vmcnt(0)" : "=v"(v) : "v"(p) : "memory");
  return v;
}
// ---- XCD-local (sc0-only) primitives — used ONLY after probe validation ----
DEV s16x8 ld16_x(const short* p){
  s16x8 v; asm volatile("global_load_dwordx4 %0, %1, off sc0" : "=v"(v) : "v"(p) : "memory"); return v;
}
DEV void st4_x(short* p, u32 v){
  asm volatile("global_store_dword %0, %1, off sc0" :: "v"(p), "v"(v) : "memory");
}
DEV void st2_x(short* p, u32 v){
  asm volatile("global_store_short %0, %1, off sc0" :: "v"(p), "v"(v) : "memory");
}
DEV void stflag_x(u32* p, u32 v){
  asm volatile("global_store_dword %0, %1, off sc0" :: "v"(p), "v"(v) : "memory");
}
DEV u32 ldflag_wait_x(const u32* p){
  u32 v; asm volatile("global_load_dword %0, %1, off sc0\ns_waitcnt vmcnt(0)" : "=v"(v) : "v"(p) : "memory");
  return v;
}
DEV void stprobe(u32* p, u32 v){
  asm volatile("global_store_dword %0, %1, off sc0" :: "v"(p), "v"(v) : "memory");
}
DEV u32 ldprobe(const u32* p){
  u32 v; asm volatile("global_load_dword %0, %1, off sc0\ns_waitcnt vmcnt(0)" : "=v"(v) : "v"(p) : "memory");
  return v;
}
// dual-path data helpers (fast is wave-uniform)
DEV s16x8 ld16f(bool fast, const short* p){ return fast ? ld16_x(p) : ldg_cc16(p); }
DEV void st4f(bool fast, short* p, u32 v){
  if (fast) st4_x(p, v);
  else asm volatile("global_store_dword %0, %1, off sc0 sc1" :: "v"(p), "v"(v) : "memory");
}
DEV void st2f(bool fast, short* p, u32 v){ if (fast) st2_x(p, v); else stg_cc2(p, v); }

// ---- explicit-AGPR weight residency (r6, proven) ---------------------------
#define LDW(R, ADDR) asm volatile("global_load_dwordx4 " R ", %0, off" :: "v"(ADDR))
#define MFMA_A(ACC, AF, R) \
  asm volatile("v_mfma_f32_16x16x32_bf16 %0, %1, " R ", %0" : "+v"(ACC) : "v"(AF))
#define MFMA_V(ACC, AF, BV) \
  asm volatile("v_mfma_f32_16x16x32_bf16 %0, %1, %2, %0" : "+v"(ACC) : "v"(AF), "v"(BV))
#define MFMA_AZ(D, AF, R, Z) \
  asm volatile("v_mfma_f32_16x16x32_bf16 %0, %1, " R ", %2" : "=&v"(D) : "v"(AF), "v"(Z))
#define POST_NOPS() asm volatile("s_nop 7\ns_nop 7\ns_nop 1") // MFMA D -> VALU read
#define LD8(V, P) V = *(const s16x8*)((P) + lane*8)

// LLC flag-line barrier (r9, proven). flags: [0..15]
template<int NOUT>
DEV void groupbar_llc(u32* flags, int w, u32 target, int tid){
  if constexpr (NOUT == 0)      asm volatile("s_waitcnt vmcnt(0)" ::: "memory");
  else if constexpr (NOUT == 1) asm volatile("s_waitcnt vmcnt(1)" ::: "memory");
  else                          asm volatile("s_waitcnt vmcnt(2)" ::: "memory");
  __syncthreads();
  if (tid == 0) stflag_llc(flags + w, target);
  if (tid < 64){
    const u32* p = flags + (tid & 15);
    while (true){
      u32 v = ldflag_wait_llc(p);
      if (__all((int)(v >= target))) break;
      __builtin_amdgcn_s_sleep(1);
    }
  }
  __syncthreads();
}

// dual-mode barrier (r10, proven). [0..15] primary, [16..31] LLC twin.
template<int NOUT>
DEV void groupbar2(bool fast, u32* flags, u32* encf, int w, u32 target, int tid){
  if constexpr (NOUT == 0)      asm volatile("s_waitcnt vmcnt(0)" ::: "memory");
  else if constexpr (NOUT == 1) asm volatile("s_waitcnt vmcnt(1)" ::: "memory");
  else                          asm volatile("s_waitcnt vmcnt(2)" ::: "memory");
  __syncthreads();
  if (tid == 0){
    if (encf) stflag_llc(encf + w, target);
    if (fast){ stflag_x(flags + w, target); stflag_llc(flags + 16 + w, target); }
    else stflag_llc(flags + w, target);
  }
  if (tid < 64){
    if (fast){
      const u32* p  = flags + (tid & 15);
      const u32* p2 = flags + 16 + (tid & 15);
      u32 it = 0;
      while (true){
        u32 v = ldflag_wait_x(p);
        if (__all((int)(v >= target))) break;
        if (((++it) & 511u) == 0u){
          u32 v2 = ldflag_wait_llc(p2);
          if (__all((int)(v2 >= target))) break;
        }
      }
    } else {
      const u32* p = flags + (tid & 15);
      while (true){
        u32 v = ldflag_wait_llc(p);
        if (__all((int)(v >= target))) break;
        __builtin_amdgcn_s_sleep(1);
      }
    }
  }
  __syncthreads();
}

// decoder waits for encoder progress with a MONOTONE per-thread snapshot:
// in steady state (enc far ahead) this is ZERO memory traffic and no sync.
DEV void wait_enc2(const u32* flags, u32 target, int tid, u32 &snap){
  if (__all((int)(snap >= target))) return;
  const u32* p = flags + (tid & 15);
  while (true){
    u32 v = ldflag_wait_llc(p);
    if (__all((int)(v >= target))){ snap = v; break; }
    __builtin_amdgcn_s_sleep(1);
  }
}

// ---------------------------------------------------------------------------
// XCD-coherence probe (r10, proven)
// ---------------------------------------------------------------------------
DEV bool probe_xcd(u32* prb, u32* pbf, u32* okf, int w, int tid, int* sscr){
  bool ok = true;
  #pragma unroll 1
  for (int round = 0; round < 2; ++round){
    const u32 salt = round ? 0xA5A5A5A5u : 0x5A5A5A5Au;
    u32 val = salt ^ ((u32)w << 20) ^ ((u32)tid * 2654435761u);
    stprobe(prb + w*256 + tid, val);
    groupbar_llc<0>(pbf, w, (u32)(round*2 + 1), tid);
    #pragma unroll 1
    for (int s = 0; s < 16; ++s){
      u32 exp = salt ^ ((u32)s << 20) ^ ((u32)tid * 2654435761u);
      u32 got = ldprobe(prb + s*256 + tid);
      ok &= (got == exp);
    }
    groupbar_llc<0>(pbf, w, (u32)(round*2 + 2), tid);
  }
  unsigned long long b = __ballot(ok);
  if ((tid & 63) == 0) sscr[tid >> 6] = (b == ~0ull) ? 1 : 0;
  __syncthreads();
  const int wgok = sscr[0] & sscr[1] & sscr[2] & sscr[3];
  __syncthreads();
  if (tid == 0) stflag_llc(okf + w, (u32)(1 + wgok));
  int fastv = 0;
  if (tid < 64){
    const u32* p = okf + (tid & 15);
    u32 v = 0;
    while (true){
      v = ldflag_wait_llc(p);
      if (__all((int)(v >= 1u))) break;
      __builtin_amdgcn_s_sleep(1);
    }
    fastv = __all((int)(v == 2u)) ? 1 : 0;
  }
  __syncthreads();
  if (tid == 0) sscr[4] = fastv;
  __syncthreads();
  return sscr[4] != 0;
}

// ---------------------------------------------------------------------------
// Fused 2-cell LSTM scan (r10 dataflow). MFMA clusters are software-pipelined:
// 4-fragment LDS load groups alternate with 8-MFMA groups, next group's loads
// issued BEFORE current group's asm MFMAs (loads overlap under lgkmcnt).
// ---------------------------------------------------------------------------
template<int KXB, bool DEC>
DEV void run_scan(const short* __restrict__ xsrc,  // [T][4][KXB][512]
                  short* __restrict__ seq,         // [T+1][4][8][512]
                  short* __restrict__ h1f,         // [2][4][16][512]
                  const short* __restrict__ w1p,
                  const short* __restrict__ w2p,
                  const float* __restrict__ bc1,
                  const float* __restrict__ bc2,
                  u32* mybar, u32* encf, bool fast,
                  int bg, int w,
                  short* lx, short* lh1, short* lh2,
                  float* g1, float* g2, float* c1s, float* c2s,
                  float* b1s, float* b2s)
{
  constexpr int KS1 = KXB + 16;
  constexpr int XB  = KXB/4;
  const int tid  = threadIdx.x;
  const int wv   = tid >> 6;
  const int lane = tid & 63;

  // ---- reserve the ENTIRE AGPR file (forces .agpr_count=256) ----
  i32x16 ag0,ag1,ag2,ag3,ag4,ag5,ag6,ag7,ag8,ag9,ag10,ag11,ag12,ag13,ag14,ag15;
  asm volatile("" : "=a"(ag0),"=a"(ag1),"=a"(ag2),"=a"(ag3),
                    "=a"(ag4),"=a"(ag5),"=a"(ag6),"=a"(ag7));
  asm volatile("" : "=a"(ag8),"=a"(ag9),"=a"(ag10),"=a"(ag11),
                    "=a"(ag12),"=a"(ag13),"=a"(ag14),"=a"(ag15));

  for (int i = tid; i < 16*32; i += 256) c1s[i] = 0.f;
  for (int i = tid; i < 16*16; i += 256) c2s[i] = 0.f;
  if (tid < 128) b1s[tid] = bc1[(tid>>5)*512 + w*32 + (tid&31)];
  if (tid < 64)  b2s[tid] = bc2[(tid>>4)*256 + w*16 + (tid&15)];

  // ---- weights -> architectural AGPRs (one-time, r6 verbatim) ----
  const int nt0 = wv*32 + w*2;
  const int nt2 = wv*16 + w;
  s16x8 W2v[8];                 // dec-only tail (32 VGPRs)
  {
    const short* b0 = w1p + (size_t)(nt0  )*KS1*512 + lane*8;
    const short* b1 = w1p + (size_t)(nt0+1)*KS1*512 + lane*8;
    const short* b2 = w2p + (size_t)nt2*24*512 + lane*8;
    if constexpr (!DEC){
      LDW("a[0:3]",   b0+0*512);  LDW("a[4:7]",   b0+1*512);  LDW("a[8:11]",  b0+2*512);  LDW("a[12:15]", b0+3*512);
      LDW("a[16:19]", b0+4*512);  LDW("a[20:23]", b0+5*512);  LDW("a[24:27]", b0+6*512);  LDW("a[28:31]", b0+7*512);
      LDW("a[32:35]", b0+8*512);  LDW("a[36:39]", b0+9*512);  LDW("a[40:43]", b0+10*512); LDW("a[44:47]", b0+11*512);
      LDW("a[48:51]", b0+12*512); LDW("a[52:55]", b0+13*512); LDW("a[56:59]", b0+14*512); LDW("a[60:63]", b0+15*512);
      LDW("a[64:67]", b0+16*512); LDW("a[68:71]", b0+17*512); LDW("a[72:75]", b0+18*512); LDW("a[76:79]", b0+19*512);
      LDW("a[80:83]",  b1+0*512);  LDW("a[84:87]",  b1+1*512);  LDW("a[88:91]",  b1+2*512);  LDW("a[92:95]",  b1+3*512);
      LDW("a[96:99]",  b1+4*512);  LDW("a[100:103]",b1+5*512);  LDW("a[104:107]",b1+6*512);  LDW("a[108:111]",b1+7*512);
      LDW("a[112:115]",b1+8*512);  LDW("a[116:119]",b1+9*512);  LDW("a[120:123]",b1+10*512); LDW("a[124:127]",b1+11*512);
      LDW("a[128:131]",b1+12*512); LDW("a[132:135]",b1+13*512); LDW("a[136:139]",b1+14*512); LDW("a[140:143]",b1+15*512);
      LDW("a[144:147]",b1+16*512); LDW("a[148:151]",b1+17*512); LDW("a[152:155]",b1+18*512); LDW("a[156:159]",b1+19*512);
      LDW("a[160:163]",b2+0*512);  LDW("a[164:167]",b2+1*512);  LDW("a[168:171]",b2+2*512);  LDW("a[172:175]",b2+3*512);
      LDW("a[176:179]",b2+4*512);  LDW("a[180:183]",b2+5*512);  LDW("a[184:187]",b2+6*512);  LDW("a[188:191]",b2+7*512);
      LDW("a[192:195]",b2+8*512);  LDW("a[196:199]",b2+9*512);  LDW("a[200:203]",b2+10*512); LDW("a[204:207]",b2+11*512);
      LDW("a[208:211]",b2+12*512); LDW("a[212:215]",b2+13*512); LDW("a[216:219]",b2+14*512); LDW("a[220:223]",b2+15*512);
      LDW("a[224:227]",b2+16*512); LDW("a[228:231]",b2+17*512); LDW("a[232:235]",b2+18*512); LDW("a[236:239]",b2+19*512);
      LDW("a[240:243]",b2+20*512); LDW("a[244:247]",b2+21*512); LDW("a[248:251]",b2+22*512); LDW("a[252:255]",b2+23*512);
    } else {
      LDW("a[0:3]",   b0+0*512);  LDW("a[4:7]",   b0+1*512);  LDW("a[8:11]",  b0+2*512);  LDW("a[12:15]", b0+3*512);
      LDW("a[16:19]", b0+4*512);  LDW("a[20:23]", b0+5*512);  LDW("a[24:27]", b0+6*512);  LDW("a[28:31]", b0+7*512);
      LDW("a[32:35]", b0+8*512);  LDW("a[36:39]", b0+9*512);  LDW("a[40:43]", b0+10*512); LDW("a[44:47]", b0+11*512);
      LDW("a[48:51]", b0+12*512); LDW("a[52:55]", b0+13*512); LDW("a[56:59]", b0+14*512); LDW("a[60:63]", b0+15*512);
      LDW("a[64:67]", b0+16*512); LDW("a[68:71]", b0+17*512); LDW("a[72:75]", b0+18*512); LDW("a[76:79]", b0+19*512);
      LDW("a[80:83]", b0+20*512); LDW("a[84:87]", b0+21*512); LDW("a[88:91]", b0+22*512); LDW("a[92:95]", b0+23*512);
      LDW("a[96:99]",  b1+0*512);  LDW("a[100:103]",b1+1*512);  LDW("a[104:107]",b1+2*512);  LDW("a[108:111]",b1+3*512);
      LDW("a[112:115]",b1+4*512);  LDW("a[116:119]",b1+5*512);  LDW("a[120:123]",b1+6*512);  LDW("a[124:127]",b1+7*512);
      LDW("a[128:131]",b1+8*512);  LDW("a[132:135]",b1+9*512);  LDW("a[136:139]",b1+10*512); LDW("a[140:143]",b1+11*512);
      LDW("a[144:147]",b1+12*512); LDW("a[148:151]",b1+13*512); LDW("a[152:155]",b1+14*512); LDW("a[156:159]",b1+15*512);
      LDW("a[160:163]",b1+16*512); LDW("a[164:167]",b1+17*512); LDW("a[168:171]",b1+18*512); LDW("a[172:175]",b1+19*512);
      LDW("a[176:179]",b1+20*512); LDW("a[180:183]",b1+21*512); LDW("a[184:187]",b1+22*512); LDW("a[188:191]",b1+23*512);
      LDW("a[192:195]",b2+0*512);  LDW("a[196:199]",b2+1*512);  LDW("a[200:203]",b2+2*512);  LDW("a[204:207]",b2+3*512);
      LDW("a[208:211]",b2+4*512);  LDW("a[212:215]",b2+5*512);  LDW("a[216:219]",b2+6*512);  LDW("a[220:223]",b2+7*512);
      LDW("a[224:227]",b2+8*512);  LDW("a[228:231]",b2+9*512);  LDW("a[232:235]",b2+10*512); LDW("a[236:239]",b2+11*512);
      LDW("a[240:243]",b2+12*512); LDW("a[244:247]",b2+13*512); LDW("a[248:251]",b2+14*512); LDW("a[252:255]",b2+15*512);
      #pragma unroll
      for (int i = 0; i < 8; ++i){
        W2v[i] = *(const s16x8*)(b2 + (16+i)*512);
        pin_v(W2v[i]);
      }
    }
    asm volatile("s_waitcnt vmcnt(0)" ::: "memory");
  }

  // persistent zero C-operand
  f32x4 zz = {0.f,0.f,0.f,0.f};
  asm volatile("" : "+v"(zz));

  u32 encSnap = 0;   // dec: monotone snapshot of enc progress flags

  // ---- prologue: stage h1_{-1} (zeros, parity 1) and x_0 ----
  {
    const short* h1src = h1f + (1*4 + bg)*16*512 + lane*8;
    s16x8 bh1[4];
    #pragma unroll
    for (int c = 0; c < 4; ++c) bh1[c] = ldg_cc16(h1src + (c*4+wv)*512);
    if constexpr (DEC) wait_enc2(encf, 2u, tid, encSnap);   // z_0 drained
    const short* xs = xsrc + (0*4 + bg)*KXB*512 + lane*8;
    s16x8 bx[XB];
    #pragma unroll
    for (int c = 0; c < XB; ++c)
      bx[c] = DEC ? ldg_cc16(xs + (c*4+wv)*512)
                  : *(const s16x8*)(xs + (c*4+wv)*512);
    wait_vm0();
    #pragma unroll
    for (int c = 0; c < 4; ++c) *(s16x8*)(lh1 + (c*4+wv)*512 + lane*8) = bh1[c];
    #pragma unroll
    for (int c = 0; c < XB; ++c) *(s16x8*)(lx + (c*4+wv)*512 + lane*8) = bx[c];
  }
  __syncthreads();

  for (int t = 0; t < T_; ++t){
    // ---- cell1: software-pipelined load/MFMA groups ----
    f32x4 a0a, a0b, a1a, a1b;
    {
      s16x8 p0,p1,p2,p3,q0,q1,q2,q3;
      if constexpr (!DEC){
        LD8(p0, lx +0*512); LD8(p1, lx +1*512); LD8(p2, lx +2*512); LD8(p3, lx +3*512);
        LD8(q0, lh1+0*512); LD8(q1, lh1+1*512); LD8(q2, lh1+2*512); LD8(q3, lh1+3*512);
        MFMA_AZ(a0a,p0,"a[0:3]",zz);   MFMA_AZ(a1a,p0,"a[80:83]",zz);
        MFMA_AZ(a0b,p1,"a[4:7]",zz);   MFMA_AZ(a1b,p1,"a[84:87]",zz);
        MFMA_A (a0a,p2,"a[8:11]");     MFMA_A (a1a,p2,"a[88:91]");
        MFMA_A (a0b,p3,"a[12:15]");    MFMA_A (a1b,p3,"a[92:95]");
        LD8(p0, lh1+4*512); LD8(p1, lh1+5*512); LD8(p2, lh1+6*512); LD8(p3, lh1+7*512);
        MFMA_A(a0a,q0,"a[16:19]"); MFMA_A(a1a,q0,"a[96:99]");
        MFMA_A(a0b,q1,"a[20:23]"); MFMA_A(a1b,q1,"a[100:103]");
        MFMA_A(a0a,q2,"a[24:27]"); MFMA_A(a1a,q2,"a[104:107]");
        MFMA_A(a0b,q3,"a[28:31]"); MFMA_A(a1b,q3,"a[108:111]");
        LD8(q0, lh1+8*512); LD8(q1, lh1+9*512); LD8(q2, lh1+10*512); LD8(q3, lh1+11*512);
        MFMA_A(a0a,p0,"a[32:35]"); MFMA_A(a1a,p0,"a[112:115]");
        MFMA_A(a0b,p1,"a[36:39]"); MFMA_A(a1b,p1,"a[116:119]");
        MFMA_A(a0a,p2,"a[40:43]"); MFMA_A(a1a,p2,"a[120:123]");
        MFMA_A(a0b,p3,"a[44:47]"); MFMA_A(a1b,p3,"a[124:127]");
        LD8(p0, lh1+12*512); LD8(p1, lh1+13*512); LD8(p2, lh1+14*512); LD8(p3, lh1+15*512);
        MFMA_A(a0a,q0,"a[48:51]"); MFMA_A(a1a,q0,"a[128:131]");
        MFMA_A(a0b,q1,"a[52:55]"); MFMA_A(a1b,q1,"a[132:135]");
        MFMA_A(a0a,q2,"a[56:59]"); MFMA_A(a1a,q2,"a[136:139]");
        MFMA_A(a0b,q3,"a[60:63]"); MFMA_A(a1b,q3,"a[140:143]");
        MFMA_A(a0a,p0,"a[64:67]"); MFMA_A(a1a,p0,"a[144:147]");
        MFMA_A(a0b,p1,"a[68:71]"); MFMA_A(a1b,p1,"a[148:151]");
        MFMA_A(a0a,p2,"a[72:75]"); MFMA_A(a1a,p2,"a[152:155]");
        MFMA_A(a0b,p3,"a[76:79]"); MFMA_A(a1b,p3,"a[156:159]");
      } else {
        LD8(p0, lx +0*512); LD8(p1, lx +1*512); LD8(p2, lx +2*512); LD8(p3, lx +3*512);
        LD8(q0, lx +4*512); LD8(q1, lx +5*512); LD8(q2, lx +6*512); LD8(q3, lx +7*512);
        MFMA_AZ(a0a,p0,"a[0:3]",zz);   MFMA_AZ(a1a,p0,"a[96:99]",zz);
        MFMA_AZ(a0b,p1,"a[4:7]",zz);   MFMA_AZ(a1b,p1,"a[100:103]",zz);
        MFMA_A (a0a,p2,"a[8:11]");     MFMA_A (a1a,p2,"a[104:107]");
        MFMA_A (a0b,p3,"a[12:15]");    MFMA_A (a1b,p3,"a[108:111]");
        LD8(p0, lh1+0*512); LD8(p1, lh1+1*512); LD8(p2, lh1+2*512); LD8(p3, lh1+3*512);
        MFMA_A(a0a,q0,"a[16:19]"); MFMA_A(a1a,q0,"a[112:115]");
        MFMA_A(a0b,q1,"a[20:23]"); MFMA_A(a1b,q1,"a[116:119]");
        MFMA_A(a0a,q2,"a[24:27]"); MFMA_A(a1a,q2,"a[120:123]");
        MFMA_A(a0b,q3,"a[28:31]"); MFMA_A(a1b,q3,"a[124:127]");
        LD8(q0, lh1+4*512); LD8(q1, lh1+5*512); LD8(q2, lh1+6*512); LD8(q3, lh1+7*512);
        MFMA_A(a0a,p0,"a[32:35]"); MFMA_A(a1a,p0,"a[128:131]");
        MFMA_A(a0b,p1,"a[36:39]"); MFMA_A(a1b,p1,"a[132:135]");
        MFMA_A(a0a,p2,"a[40:43]"); MFMA_A(a1a,p2,"a[136:139]");
        MFMA_A(a0b,p3,"a[44:47]"); MFMA_A(a1b,p3,"a[140:143]");
        LD8(p0, lh1+8*512); LD8(p1, lh1+9*512); LD8(p2, lh1+10*512); LD8(p3, lh1+11*512);
        MFMA_A(a0a,q0,"a[48:51]"); MFMA_A(a1a,q0,"a[144:147]");
        MFMA_A(a0b,q1,"a[52:55]"); MFMA_A(a1b,q1,"a[148:151]");
        MFMA_A(a0a,q2,"a[56:59]"); MFMA_A(a1a,q2,"a[152:155]");
        MFMA_A(a0b,q3,"a[60:63]"); MFMA_A(a1b,q3,"a[156:159]");
        LD8(q0, lh1+12*512); LD8(q1, lh1+13*512); LD8(q2, lh1+14*512); LD8(q3, lh1+15*512);
        MFMA_A(a0a,p0,"a[64:67]"); MFMA_A(a1a,p0,"a[160:163]");
        MFMA_A(a0b,p1,"a[68:71]"); MFMA_A(a1b,p1,"a[164:167]");
        MFMA_A(a0a,p2,"a[72:75]"); MFMA_A(a1a,p2,"a[168:171]");
        MFMA_A(a0b,p3,"a[76:79]"); MFMA_A(a1b,p3,"a[172:175]");
        MFMA_A(a0a,q0,"a[80:83]"); MFMA_A(a1a,q0,"a[176:179]");
        MFMA_A(a0b,q1,"a[84:87]"); MFMA_A(a1b,q1,"a[180:183]");
        MFMA_A(a0a,q2,"a[88:91]"); MFMA_A(a1a,q2,"a[184:187]");
        MFMA_A(a0b,q3,"a[92:95]"); MFMA_A(a1b,q3,"a[188:191]");
      }
    }
    POST_NOPS();
    {
      const f32x4 acc0 = a0a + a0b, acc1 = a1a + a1b;
      const int r0 = (lane>>4)*4, cc = lane & 15;
      #pragma unroll
      for (int j = 0; j < 4; ++j){
        g1[wv*528 + (r0+j)*33 + cc]      = acc0[j];
        g1[wv*528 + (r0+j)*33 + 16 + cc] = acc1[j];
      }
    }
    __syncthreads();

    // ---- elementwise: h1 slice ----
    {
      short* h1dst = h1f + (((t&1)*4 + bg)*16 + w)*512;
      const int idx = tid << 1;
      const int r = idx >> 5;
      const int c = idx & 31;
      float hv0 = 0.f, hv1 = 0.f;
      #pragma unroll
      for (int p = 0; p < 2; ++p){
        const int cp = c + p;
        const float xi = g1[0*528 + r*33+cp] + b1s[0*32+cp];
        const float xf = g1[1*528 + r*33+cp] + b1s[1*32+cp];
        const float xg = g1[2*528 + r*33+cp] + b1s[2*32+cp];
        const float xo = g1[3*528 + r*33+cp] + b1s[3*32+cp];
        const float ii = sigm_(xi), ff = sigm_(xf), oo = sigm_(xo);
        const float gg = tanh_(xg);
        const float cn = ff * c1s[r*32+cp] + ii * gg;
        c1s[r*32+cp] = cn;
        const float hv = oo * tanh_(cn);
        if (p == 0) hv0 = hv; else hv1 = hv;
      }
      const u32 pk = bf16rne(hv0) | (bf16rne(hv1) << 16);
      st4f(fast, h1dst + ((((c>>3)<<4) + r) << 3) + (c & 7), pk);
    }

    // ---- enc-progress (cached snapshot) + next x/z prefetch ----
    const int tn = (t+1 < T_) ? (t+1) : (T_-1);
    if constexpr (DEC) wait_enc2(encf, (u32)(tn+2), tid, encSnap);
    s16x8 bx[XB];
    {
      const short* xs = xsrc + (tn*4 + bg)*KXB*512 + lane*8;
      #pragma unroll
      for (int c = 0; c < XB; ++c)
        bx[c] = DEC ? ldg_cc16(xs + (c*4+wv)*512)
                    : *(const s16x8*)(xs + (c*4+wv)*512);
    }

    groupbar2<XB>(fast, mybar, DEC ? nullptr : encf, w, (u32)(t+1), tid);

    // ---- stage: h1_t, h2_{t-1}; x from prefetch ----
    {
      const short* h1src = h1f + ((t&1)*4 + bg)*16*512 + lane*8;
      const short* h2src = seq + (t*4 + bg)*8*512 + lane*8;
      s16x8 bh1[4], bh2[2];
      #pragma unroll
      for (int c = 0; c < 4; ++c) bh1[c] = ld16f(fast, h1src + (c*4+wv)*512);
      #pragma unroll
      for (int c = 0; c < 2; ++c)
        bh2[c] = DEC ? ld16f(fast, h2src + (c*4+wv)*512)
                     : ldg_cc16(h2src + (c*4+wv)*512);
      wait_vm0();
      #pragma unroll
      for (int c = 0; c < 4; ++c) *(s16x8*)(lh1 + (c*4+wv)*512 + lane*8) = bh1[c];
      #pragma unroll
      for (int c = 0; c < 2; ++c) *(s16x8*)(lh2 + (c*4+wv)*512 + lane*8) = bh2[c];
      #pragma unroll
      for (int c = 0; c < XB; ++c) *(s16x8*)(lx + (c*4+wv)*512 + lane*8) = bx[c];
    }
    __syncthreads();

    // ---- cell2: software-pipelined load/MFMA groups ----
    f32x4 aca, acb;
    {
      s16x8 p0,p1,p2,p3,q0,q1,q2,q3;
      if constexpr (!DEC){
        LD8(p0, lh1+0*512); LD8(p1, lh1+1*512); LD8(p2, lh1+2*512); LD8(p3, lh1+3*512);
        LD8(q0, lh1+4*512); LD8(q1, lh1+5*512); LD8(q2, lh1+6*512); LD8(q3, lh1+7*512);
        MFMA_AZ(aca,p0,"a[160:163]",zz); MFMA_AZ(acb,p1,"a[164:167]",zz);
        MFMA_A (aca,p2,"a[168:171]");    MFMA_A (acb,p3,"a[172:175]");
        LD8(p0, lh1+8*512); LD8(p1, lh1+9*512); LD8(p2, lh1+10*512); LD8(p3, lh1+11*512);
        MFMA_A(aca,q0,"a[176:179]"); MFMA_A(acb,q1,"a[180:183]");
        MFMA_A(aca,q2,"a[184:187]"); MFMA_A(acb,q3,"a[188:191]");
        LD8(q0, lh1+12*512); LD8(q1, lh1+13*512); LD8(q2, lh1+14*512); LD8(q3, lh1+15*512);
        MFMA_A(aca,p0,"a[192:195]"); MFMA_A(acb,p1,"a[196:199]");
        MFMA_A(aca,p2,"a[200:203]"); MFMA_A(acb,p3,"a[204:207]");
        LD8(p0, lh2+0*512); LD8(p1, lh2+1*512); LD8(p2, lh2+2*512); LD8(p3, lh2+3*512);
        MFMA_A(aca,q0,"a[208:211]"); MFMA_A(acb,q1,"a[212:215]");
        MFMA_A(aca,q2,"a[216:219]"); MFMA_A(acb,q3,"a[220:223]");
        LD8(q0, lh2+4*512); LD8(q1, lh2+5*512); LD8(q2, lh2+6*512); LD8(q3, lh2+7*512);
        MFMA_A(aca,p0,"a[224:227]"); MFMA_A(acb,p1,"a[228:231]");
        MFMA_A(aca,p2,"a[232:235]"); MFMA_A(acb,p3,"a[236:239]");
        MFMA_A(aca,q0,"a[240:243]"); MFMA_A(acb,q1,"a[244:247]");
        MFMA_A(aca,q2,"a[248:251]"); MFMA_A(acb,q3,"a[252:255]");
      } else {
        LD8(p0, lh1+0*512); LD8(p1, lh1+1*512); LD8(p2, lh1+2*512); LD8(p3, lh1+3*512);
        LD8(q0, lh1+4*512); LD8(q1, lh1+5*512); LD8(q2, lh1+6*512); LD8(q3, lh1+7*512);
        MFMA_AZ(aca,p0,"a[192:195]",zz); MFMA_AZ(acb,p1,"a[196:199]",zz);
        MFMA_A (aca,p2,"a[200:203]");    MFMA_A (acb,p3,"a[204:207]");
        LD8(p0, lh1+8*512); LD8(p1, lh1+9*512); LD8(p2, lh1+10*512); LD8(p3, lh1+11*512);
        MFMA_A(aca,q0,"a[208:211]"); MFMA_A(acb,q1,"a[212:215]");
        MFMA_A(aca,q2,"a[216:219]"); MFMA_A(acb,q3,"a[220:223]");
        LD8(q0, lh1+12*512); LD8(q1, lh1+13*512); LD8(q2, lh1+14*512); LD8(q3, lh1+15*512);
        MFMA_A(aca,p0,"a[224:227]"); MFMA_A(acb,p1,"a[228:231]");
        MFMA_A(aca,p2,"a[232:235]"); MFMA_A(acb,p3,"a[236:239]");
        LD8(p0, lh2+0*512); LD8(p1, lh2+1*512); LD8(p2, lh2+2*512); LD8(p3, lh2+3*512);
        MFMA_A(aca,q0,"a[240:243]"); MFMA_A(acb,q1,"a[244:247]");
        MFMA_A(aca,q2,"a[248:251]"); MFMA_A(acb,q3,"a[252:255]");
        LD8(q0, lh2+4*512); LD8(q1, lh2+5*512); LD8(q2, lh2+6*512); LD8(q3, lh2+7*512);
        MFMA_V(aca,p0,W2v[0]); MFMA_V(acb,p1,W2v[1]);
        MFMA_V(aca,p2,W2v[2]); MFMA_V(acb,p3,W2v[3]);
        MFMA_V(aca,q0,W2v[4]); MFMA_V(acb,q1,W2v[5]);
        MFMA_V(aca,q2,W2v[6]); MFMA_V(acb,q3,W2v[7]);
      }
    }
    POST_NOPS();
    {
      const f32x4 acc = aca + acb;
      const int r0 = (lane>>4)*4, cc = lane & 15;
      #pragma unroll
      for (int j = 0; j < 4; ++j) g2[wv*272 + (r0+j)*17 + cc] = acc[j];
    }
    __syncthreads();
    {
      short* odst = seq + ((t+1)*4 + bg)*8*512;
      const int r = tid >> 4, c = tid & 15;
      const float xi = g2[0*272 + r*17+c] + b2s[0*16+c];
      const float xf = g2[1*272 + r*17+c] + b2s[1*16+c];
      const float xg = g2[2*272 + r*17+c] + b2s[2*16+c];
      const float xo = g2[3*272 + r*17+c] + b2s[3*16+c];
      const float ii = sigm_(xi), ff = sigm_(xf), oo = sigm_(xo);
      const float gg = tanh_(xg);
      const float cn = ff * c2s[r*16+c] + ii * gg;
      c2s[r*16+c] = cn;
      const float hv = oo * tanh_(cn);
      const int jj = ((w & 1) << 4) + c;
      const int off = (((w>>1)*64 + ((jj>>3)<<4) + r) << 3) + (jj & 7);
      if constexpr (DEC) st2f(fast, odst + off, bf16rne(hv));
      else stg_cc2(odst + off, bf16rne(hv));   // cross-group: dec reads via LLC
    }
  }

  if constexpr (!DEC){
    wait_vm0();
    __syncthreads();
    if (tid == 0) stflag_llc(encf + w, (u32)(T_+1));
  }

  asm volatile("" :: "a"(ag0),"a"(ag1),"a"(ag2),"a"(ag3),
                     "a"(ag4),"a"(ag5),"a"(ag6),"a"(ag7));
  asm volatile("" :: "a"(ag8),"a"(ag9),"a"(ag10),"a"(ag11),
                     "a"(ag12),"a"(ag13),"a"(ag14),"a"(ag15));
}

// group gg = blockIdx&7 (16 WGs, stride 8 -> one XCD under round-robin
// dispatch; verified by the probe, NOT assumed). gg 0..3 enc, 4..7 dec.
__launch_bounds__(256, 1)
__global__ void scan2(const short* __restrict__ xp,
                      short* __restrict__ zfrag, short* __restrict__ dfrag,
                      short* __restrict__ h1e, short* __restrict__ h1d,
                      const short* __restrict__ enc1p, const short* __restrict__ enc2p,
                      const short* __restrict__ dec1p, const short* __restrict__ dec2p,
                      const float* __restrict__ bc1e, const float* __restrict__ bc2e,
                      const float* __restrict__ bc1d, const float* __restrict__ bc2d,
                      u32* __restrict__ bar, u32* __restrict__ prb)
{
  __shared__ short lx[8*512];
  __shared__ short lh1[16*512];
  __shared__ short lh2[8*512];
  __shared__ float g1[4*528];
  __shared__ float g2[4*272];
  __shared__ float c1s[16*32];
  __shared__ float c2s[16*16];
  __shared__ float b1s[128];
  __shared__ float b2s[64];
  __shared__ int sscr[8];

  const int b  = blockIdx.x;
  const int gg = b & 7;
  const int w  = b >> 3;
  const bool isdec = (gg >= 4);
  const int bg = isdec ? (gg - 4) : gg;

  const bool fast = probe_xcd(prb + gg*4096, bar + 1024 + gg*16,
                              bar + 1280 + gg*16, w, threadIdx.x, sscr);

  u32* myflags = bar + gg*32;           // [0..15] primary, [16..31] LLC twin
  u32* encf    = bar + 512 + bg*16;     // enc progress (LLC, cross-group)

  if (!isdec){
    run_scan<4, false>(xp, zfrag, h1e, enc1p, enc2p, bc1e, bc2e,
                       myflags, encf, fast, bg, w,
                       lx, lh1, lh2, g1, g2, c1s, c2s, b1s, b2s);
  } else {
    run_scan<8, true>(zfrag + 4*8*512, dfrag, h1d, dec1p, dec2p, bc1d, bc2d,
                      myflags, encf, fast, bg, w,
                      lx, lh1, lh2, g1, g2, c1s, c2s, b1s, b2s);
  }
}

// ---------------------------------------------------------------------------
// fused fc1(relu)+fc2 over one t-slice (64 rows) per block  (unchanged)
// ---------------------------------------------------------------------------
__launch_bounds__(256, 1)
__global__ void fc_kernel(const short* __restrict__ dfrag,
                          const short* __restrict__ fc1p,
                          const short* __restrict__ fc2p,
                          const float* __restrict__ fc1b,
                          float* __restrict__ out)
{
  const int t = blockIdx.x;
  const int tid = threadIdx.x, wv = tid >> 6, lane = tid & 63;
  __shared__ short hl[4*16*512];
  const short* A = dfrag + (size_t)(t+1)*4*8*512;

  f32x4 acc[4][8];
  #pragma unroll
  for (int mt = 0; mt < 4; ++mt)
    #pragma unroll
    for (int nt = 0; nt < 8; ++nt) acc[mt][nt] = (f32x4){0.f,0.f,0.f,0.f};

  #pragma unroll
  for (int ks = 0; ks < 8; ++ks){
    s16x8 a[4];
    #pragma unroll
    for (int mt = 0; mt < 4; ++mt) a[mt] = *(const s16x8*)(A + (mt*8+ks)*512 + lane*8);
    #pragma unroll
    for (int nt = 0; nt < 8; ++nt){
      s16x8 bq = *(const s16x8*)(fc1p + (((wv*8+nt)*8 + ks)*64 + lane)*8);
      #pragma unroll
      for (int mt = 0; mt < 4; ++mt) acc[mt][nt] = mfma_(a[mt], bq, acc[mt][nt]);
    }
  }
  const int r0 = (lane>>4)*4, c15 = lane & 15;
  #pragma unroll
  for (int nt = 0; nt < 8; ++nt){
    const int col = wv*128 + nt*16 + c15;
    const float bia = fc1b[col];
    const int ks2 = col >> 5, lp = (((col & 31) >> 3) << 4), e = col & 7;
    #pragma unroll
    for (int mt = 0; mt < 4; ++mt)
      #pragma unroll
      for (int j = 0; j < 4; ++j){
        float v = acc[mt][nt][j] + bia;
        v = v > 0.f ? v : 0.f;
        hl[(mt*16 + ks2)*512 + (lp + r0 + j)*8 + e] = (short)bf16rne(v);
      }
  }
  __syncthreads();

  f32x4 a2[4][2];
  #pragma unroll
  for (int mt = 0; mt < 4; ++mt)
    #pragma unroll
    for (int nt = 0; nt < 2; ++nt) a2[mt][nt] = (f32x4){0.f,0.f,0.f,0.f};
  #pragma unroll
  for (int ks = 0; ks < 16; ++ks){
    s16x8 a[4];
    #pragma unroll
    for (int mt = 0; mt < 4; ++mt) a[mt] = *(const s16x8*)(hl + (mt*16+ks)*512 + lane*8);
    #pragma unroll
    for (int nt = 0; nt < 2; ++nt){
      s16x8 bq = *(const s16x8*)(fc2p + (((wv*2+nt)*16 + ks)*64 + lane)*8);
      #pragma unroll
      for (int mt = 0; mt < 4; ++mt) a2[mt][nt] = mfma_(a[mt], bq, a2[mt][nt]);
    }
  }
  #pragma unroll
  for (int mt = 0; mt < 4; ++mt)
    #pragma unroll
    for (int nt = 0; nt < 2; ++nt)
      #pragma unroll
      for (int j = 0; j < 4; ++j){
        const int b_  = mt*16 + r0 + j;
        const int col = wv*32 + nt*16 + c15;
        out[((size_t)b_*1024 + t)*128 + col] = a2[mt][nt][j];
      }
}

// ---------------------------------------------------------------------------
// packing kernels (unchanged)
// ---------------------------------------------------------------------------
__global__ void pack_w(const float* __restrict__ src1, int K1,
                       const float* __restrict__ src2, int K2,
                       int N, short* __restrict__ dst)
{
  const int KS = (K1 + K2) >> 5;
  const int total = (N >> 4) * KS * 64;
  const int tid = blockIdx.x*256 + threadIdx.x;
  if (tid >= total) return;
  const int lane = tid & 63;
  const int rest = tid >> 6;
  const int ks = rest % KS;
  const int ntile = rest / KS;
  const int n = ntile*16 + (lane & 15);
  const int k = ks*32 + ((lane >> 4) << 3);
  const float* s; int kk, stride;
  if (k < K1){ s = src1; kk = k;      stride = K1; }
  else       { s = src2; kk = k - K1; stride = K2; }
  const float4 f0 = *(const float4*)(s + n*stride + kk);
  const float4 f1 = *(const float4*)(s + n*stride + kk + 4);
  s16x8 r;
  r[0] = (short)bf16rne(f0.x); r[1] = (short)bf16rne(f0.y);
  r[2] = (short)bf16rne(f0.z); r[3] = (short)bf16rne(f0.w);
  r[4] = (short)bf16rne(f1.x); r[5] = (short)bf16rne(f1.y);
  r[6] = (short)bf16rne(f1.z); r[7] = (short)bf16rne(f1.w);
  *(s16x8*)(dst + tid*8) = r;
}

__global__ void pack_x_k(const float* __restrict__ x, short* __restrict__ xp){
  const int tid = blockIdx.x*256 + threadIdx.x;
  const int lane = tid & 63;
  const int ks = (tid >> 6) & 3;
  const int bg = (tid >> 8) & 3;
  const int t  = tid >> 10;
  const int b  = bg*16 + (lane & 15);
  const int k  = ks*32 + ((lane >> 4) << 3);
  const float* s = x + (b*1024 + t)*128 + k;
  const float4 f0 = *(const float4*)s;
  const float4 f1 = *(const float4*)(s + 4);
  s16x8 r;
  r[0] = (short)bf16rne(f0.x); r[1] = (short)bf16rne(f0.y);
  r[2] = (short)bf16rne(f0.z); r[3] = (short)bf16rne(f0.w);
  r[4] = (short)bf16rne(f1.x); r[5] = (short)bf16rne(f1.y);
  r[6] = (short)bf16rne(f1.z); r[7] = (short)bf16rne(f1.w);
  *(s16x8*)(xp + (size_t)tid*8) = r;
}

__global__ void addv(const float* __restrict__ a, const float* __restrict__ b,
                     float* __restrict__ o, int n){
  const int i = blockIdx.x*256 + threadIdx.x;
  if (i < n) o[i] = a[i] + b[i];
}

// ---------------------------------------------------------------------------
extern "C" void kernel_launch(void* const* d_in, const int* in_sizes, int n_in,
                              void* d_out, int out_size, void* d_ws, size_t ws_size,
                              hipStream_t stream)
{
  (void)in_sizes; (void)n_in; (void)out_size; (void)ws_size;
  const float* x     = (const float*)d_in[0];
  const float* eWih1 = (const float*)d_in[1];
  const float* eWhh1 = (const float*)d_in[2];
  const float* ebih1 = (const float*)d_in[3];
  const float* ebhh1 = (const float*)d_in[4];
  const float* eWih2 = (const float*)d_in[5];
  const float* eWhh2 = (const float*)d_in[6];
  const float* ebih2 = (const float*)d_in[7];
  const float* ebhh2 = (const float*)d_in[8];
  const float* dWih1 = (const float*)d_in[9];
  const float* dWhh1 = (const float*)d_in[10];
  const float* dbih1 = (const float*)d_in[11];
  const float* dbhh1 = (const float*)d_in[12];
  const float* dWih2 = (const float*)d_in[13];
  const float* dWhh2 = (const float*)d_in[14];
  const float* dbih2 = (const float*)d_in[15];
  const float* dbhh2 = (const float*)d_in[16];
  const float* fc1w  = (const float*)d_in[17];
  const float* fc1b  = (const float*)d_in[18];
  const float* fc2w  = (const float*)d_in[19];
  float* out = (float*)d_out;
  char* ws = (char*)d_ws;

  size_t off = 0;
  auto alloc = [&](size_t bytes){ size_t o = off; off += (bytes + 255) & ~(size_t)255; return o; };
  const size_t ENC1P = alloc(128*20*512*2);
  const size_t ENC2P = alloc(64*24*512*2);
  const size_t DEC1P = alloc(128*24*512*2);
  const size_t DEC2P = alloc(64*24*512*2);
  const size_t FC1P  = alloc(32*8*512*2);
  const size_t FC2P  = alloc(8*16*512*2);
  const size_t BC1E  = alloc(2048*4);
  const size_t BC2E  = alloc(1024*4);
  const size_t BC1D  = alloc(2048*4);
  const size_t BC2D  = alloc(1024*4);
  const size_t XP    = alloc((size_t)1024*4*4*512*2);
  const size_t ZFRAG = alloc((size_t)1025*4*8*512*2);
  const size_t DFRAG = alloc((size_t)1025*4*8*512*2);
  const size_t H1E   = alloc(2*4*16*512*2);
  const size_t H1D   = alloc(2*4*16*512*2);
  const size_t BAR   = alloc(8192);
  const size_t PRB   = alloc(8*16384);

  short* enc1p = (short*)(ws + ENC1P);
  short* enc2p = (short*)(ws + ENC2P);
  short* dec1p = (short*)(ws + DEC1P);
  short* dec2p = (short*)(ws + DEC2P);
  short* fc1p  = (short*)(ws + FC1P);
  short* fc2p  = (short*)(ws + FC2P);
  float* bc1e  = (float*)(ws + BC1E);
  float* bc2e  = (float*)(ws + BC2E);
  float* bc1d  = (float*)(ws + BC1D);
  float* bc2d  = (float*)(ws + BC2D);
  short* xp    = (short*)(ws + XP);
  short* zfrag = (short*)(ws + ZFRAG);
  short* dfrag = (short*)(ws + DFRAG);
  short* h1e   = (short*)(ws + H1E);
  short* h1d   = (short*)(ws + H1D);
  u32*   bar   = (u32*)(ws + BAR);
  u32*   prb   = (u32*)(ws + PRB);

  hipMemsetAsync(zfrag, 0, 4*8*512*2, stream);          // z slot 0 (h2 state t=0)
  hipMemsetAsync(dfrag, 0, 4*8*512*2, stream);
  hipMemsetAsync(h1e, 0, 2*4*16*512*2, stream);
  hipMemsetAsync(h1d, 0, 2*4*16*512*2, stream);
  hipMemsetAsync(bar, 0, 8192, stream);                 // all flag lines

  pack_w<<<640, 256, 0, stream>>>(eWih1, 128, eWhh1, 512, 2048, enc1p);
  pack_w<<<384, 256, 0, stream>>>(eWih2, 512, eWhh2, 256, 1024, enc2p);
  pack_w<<<768, 256, 0, stream>>>(dWih1, 256, dWhh1, 512, 2048, dec1p);
  pack_w<<<384, 256, 0, stream>>>(dWih2, 512, dWhh2, 256, 1024, dec2p);
  pack_w<<<64,  256, 0, stream>>>(fc1w,  256, fc1w,  0,   512,  fc1p);
  pack_w<<<32,  256, 0, stream>>>(fc2w,  512, fc2w,  0,   128,  fc2p);
  addv<<<8, 256, 0, stream>>>(ebih1, ebhh1, bc1e, 2048);
  addv<<<4, 256, 0, stream>>>(ebih2, ebhh2, bc2e, 1024);
  addv<<<8, 256, 0, stream>>>(dbih1, dbhh1, bc1d, 2048);
  addv<<<4, 256, 0, stream>>>(dbih2, dbhh2, bc2d, 1024);
  pack_x_k<<<4096, 256, 0, stream>>>(x, xp);

  scan2<<<128, 256, 0, stream>>>(xp, zfrag, dfrag, h1e, h1d,
                                 enc1p, enc2p, dec1p, dec2p,
                                 bc1e, bc2e, bc1d, bc2d, bar, prb);
  fc_kernel<<<1024, 256, 0, stream>>>(dfrag, fc1p, fc2p, fc1b, out);
}